// Round 3
// baseline (1103.563 us; speedup 1.0000x reference)
//
#include <hip/hip_runtime.h>
#include <hip/hip_bf16.h>
#include <math.h>

typedef unsigned short u16;   // bf16 storage

#define B_    8
#define C_    64
#define HW_   4096
#define NPIX  32768     // B_*HW_
#define DI    128
#define NCH   16
#define CHL   256       // HW_/NCH

__device__ __forceinline__ float b2f(u16 v){ return __uint_as_float(((unsigned)v)<<16); }
__device__ __forceinline__ u16 f2b(float x){
  unsigned u = __float_as_uint(x);
  u += 0x7fff + ((u >> 16) & 1);      // RTNE
  return (u16)(u >> 16);
}
__device__ __forceinline__ float4 ld4b(const u16* p){
  ushort4 q = *(const ushort4*)p;
  return make_float4(b2f(q.x), b2f(q.y), b2f(q.z), b2f(q.w));
}
__device__ __forceinline__ float gelu_exact(float x){ return 0.5f*x*(1.0f+erff(x*0.70710678118654752f)); }
__device__ __forceinline__ float leaky02(float x){ return x>0.f ? x : 0.2f*x; }
__device__ __forceinline__ float softplus_(float x){ return fmaxf(x,0.f)+log1pf(__expf(-fabsf(x))); }

// ---------------- NCHW fp32 -> NHWC bf16 ----------------
__global__ void k_trans_in(const float* __restrict__ x, u16* __restrict__ xT){
  __shared__ float tile[64][65];
  int blk = blockIdx.x;            // B_ * (HW_/64) = 512
  int b = blk >> 6;
  int hwb = (blk & 63) << 6;
  int lane = threadIdx.x & 63, row = threadIdx.x >> 6;
  const float* src = x + (size_t)b*C_*HW_;
  #pragma unroll
  for(int k=0;k<16;k++){
    int c = row + 4*k;
    tile[c][lane] = src[c*HW_ + hwb + lane];
  }
  __syncthreads();
  u16* dst = xT + (size_t)b*HW_*C_;
  #pragma unroll
  for(int k=0;k<16;k++){
    int hwl = row + 4*k;
    dst[(hwb+hwl)*C_ + lane] = f2b(tile[lane][hwl]);
  }
}

// ---------------- NHWC fp32 -> NCHW fp32 ----------------
__global__ void k_trans_out(const float* __restrict__ xO, float* __restrict__ out){
  __shared__ float tile[64][65];
  int blk = blockIdx.x;
  int b = blk >> 6;
  int hwb = (blk & 63) << 6;
  int lane = threadIdx.x & 63, row = threadIdx.x >> 6;
  const float* src = xO + (size_t)b*HW_*C_;
  #pragma unroll
  for(int k=0;k<16;k++){
    int hwl = row + 4*k;
    tile[lane][hwl] = src[(hwb+hwl)*C_ + lane];   // tile[c][hw_local]
  }
  __syncthreads();
  float* dst = out + (size_t)b*C_*HW_;
  #pragma unroll
  for(int k=0;k<16;k++){
    int c = row + 4*k;
    dst[c*HW_ + hwb + lane] = tile[c][lane];      // FIXED: was tile[c][row+4k]
  }
}

// ---------------- LayerNorm over c=64 (one wave per pixel) ----------------
__global__ void k_ln(const u16* __restrict__ in, const float* __restrict__ g,
                     const float* __restrict__ bta, u16* __restrict__ out){
  int wid = (blockIdx.x*blockDim.x + threadIdx.x) >> 6;
  int lane = threadIdx.x & 63;
  int nw = (gridDim.x*blockDim.x) >> 6;
  float gg = g[lane], bb = bta[lane];
  for(int p = wid; p < NPIX; p += nw){
    float v = b2f(in[(size_t)p*64 + lane]);
    float s = v, sq = v*v;
    #pragma unroll
    for(int o=32;o>0;o>>=1){ s += __shfl_xor(s,o); sq += __shfl_xor(sq,o); }
    float m = s*(1.f/64.f);
    float var = sq*(1.f/64.f) - m*m;
    float r = rsqrtf(var + 1e-5f);
    out[(size_t)p*64+lane] = f2b((v-m)*r*gg + bb);
  }
}

// ---------------- generic matmul: [NPIX,CIN](bf16) @ [CIN,COUT](fp32) ----------------
// ACT: 0 none, 1 leaky(0.2), 2 softplus (after bias)
template<int CIN, int COUT, int ACT, bool OUTF32>
__global__ void k_mm(const float* __restrict__ W, int ldw, int wofs,
                     const u16* __restrict__ in, const float* __restrict__ bias,
                     const u16* __restrict__ res, void* __restrict__ outv){
  __shared__ __align__(16) float WT[COUT*CIN];   // WT[d][(c+4d)%CIN]
  for(int idx = threadIdx.x; idx < CIN*COUT; idx += 256){
    int d = idx % COUT, c = idx / COUT;
    WT[d*CIN + ((c + 4*d) & (CIN-1))] = W[(size_t)c*ldw + wofs + d];
  }
  __syncthreads();
  const int PP = 256/COUT;          // pixels per pass
  int psub = threadIdx.x / COUT;
  int d = threadIdx.x % COUT;
  int rot = (4*d) & (CIN-1);
  const float* wrow = &WT[d*CIN];
  float bs = bias ? bias[d] : 0.f;
  int passes = NPIX/PP;
  for(int pass = blockIdx.x; pass < passes; pass += gridDim.x){
    int p = pass*PP + psub;
    float acc = 0.f;
    #pragma unroll 8
    for(int j=0;j<CIN;j+=4){
      float4 a = ld4b(in + (size_t)p*CIN + j);
      int cc = (j + rot) & (CIN-1);
      float4 w = *(const float4*)(wrow + cc);
      acc += a.x*w.x + a.y*w.y + a.z*w.z + a.w*w.w;
    }
    acc += bs;
    if(ACT==1) acc = leaky02(acc);
    else if(ACT==2) acc = softplus_(acc);
    if(res) acc += b2f(res[(size_t)p*COUT + d]);
    if(OUTF32) ((float*)outv)[(size_t)p*COUT + d] = acc;
    else       ((u16*)outv)[(size_t)p*COUT + d] = f2b(acc);
  }
}

// ---------------- depthwise 3x3 SAME ----------------
template<int CN, int ACT>   // ACT: 0 none, 1 leaky, 2 gelu
__global__ void k_dw3(const u16* __restrict__ in, const float* __restrict__ wgt,
                      const u16* __restrict__ res1, const u16* __restrict__ res2,
                      u16* __restrict__ out){
  int g = blockIdx.x*256 + threadIdx.x;     // NPIX*CN threads
  int c = g % CN;
  int pix = g / CN;
  int w = pix & 63;
  int h = (pix >> 6) & 63;
  int b = pix >> 12;
  float acc = 0.f;
  #pragma unroll
  for(int kh=0;kh<3;kh++){
    int hh = h + kh - 1;
    if((unsigned)hh < 64u){
      #pragma unroll
      for(int kw=0;kw<3;kw++){
        int ww = w + kw - 1;
        if((unsigned)ww < 64u){
          acc += b2f(in[(size_t)((b*64+hh)*64 + ww)*CN + c]) * wgt[(kh*3+kw)*CN + c];
        }
      }
    }
  }
  if(ACT==1) acc = leaky02(acc);
  else if(ACT==2) acc = gelu_exact(acc);
  if(res1) acc += b2f(res1[(size_t)pix*CN + c]);
  if(res2) acc += b2f(res2[(size_t)pix*CN + c]);
  out[(size_t)pix*CN + c] = f2b(acc);
}

// ---- causal depthwise conv1d (k=4) + silu on xi cols; silu(z) extracted too ----
__global__ void k_causal(const u16* __restrict__ xz, const float* __restrict__ cw,
                         const float* __restrict__ cb, u16* __restrict__ xi,
                         u16* __restrict__ zs){
  int g = blockIdx.x*256 + threadIdx.x;     // NPIX*128
  int d = g & 127;
  int p = g >> 7;            // b*4096 + t
  int t = p & 4095;
  float acc = cb[d];
  #pragma unroll
  for(int k=0;k<4;k++){
    int tt = t + k - 3;
    if(tt >= 0) acc += b2f(xz[(size_t)(p + k - 3)*256 + d]) * cw[k*128 + d];
  }
  xi[(size_t)p*128 + d] = f2b(acc / (1.0f + __expf(-acc)));   // silu
  float z = b2f(xz[(size_t)p*256 + 128 + d]);
  zs[(size_t)p*128 + d] = f2b(z / (1.0f + __expf(-z)));       // silu(z)
}

// ---------------- fuse xproj[:, :4] @ dt_w  ->  Wf[128][128] fp32 ----------------
__global__ void k_fusew(const float* __restrict__ xproj, const float* __restrict__ dtw,
                        float* __restrict__ wf){
  int g = blockIdx.x*256 + threadIdx.x;     // 16384
  int d = g & 127;
  int c = g >> 7;
  float acc = 0.f;
  #pragma unroll
  for(int r=0;r<4;r++) acc += xproj[c*36 + r] * dtw[r*128 + d];
  wf[c*128 + d] = acc;
}

// ---------------- scan phase 1: per-chunk (P = prod a, Q = local recurrence) ----------------
__global__ void k_scan1(const u16* __restrict__ dt, const u16* __restrict__ xi,
                        const u16* __restrict__ bc, const float* __restrict__ alog,
                        float* __restrict__ Pb, float* __restrict__ Qb){
  int g = blockIdx.x*256 + threadIdx.x;     // B_*DI*16*NCH = 262144
  int s = g & 15;
  int d = (g >> 4) & 127;
  int ch = (g >> 11) & 15;
  int b = g >> 15;
  float A = -__expf(alog[d*16 + s]);
  float P = 1.f, hq = 0.f;
  int pbase = b*4096 + ch*CHL;
  for(int i=0;i<CHL;i++){
    int p = pbase + i;
    float ldt = b2f(dt[(size_t)p*128 + d]);
    float lxi = b2f(xi[(size_t)p*128 + d]);
    float lB  = b2f(bc[(size_t)p*32 + s]);
    float a = __expf(ldt*A);
    P *= a;
    hq = a*hq + ldt*lxi*lB;
  }
  int idx = ((b*128 + d)*16 + s)*16 + ch;
  Pb[idx] = P; Qb[idx] = hq;
}

// ---------------- scan phase 2: sequential over 16 chunks ----------------
__global__ void k_scan2(const float* __restrict__ Pb, const float* __restrict__ Qb,
                        float* __restrict__ Hin){
  int g = blockIdx.x*256 + threadIdx.x;     // 16384
  float h = 0.f;
  int base = g*16;
  #pragma unroll
  for(int ch=0; ch<16; ch++){
    Hin[base+ch] = h;
    h = Pb[base+ch]*h + Qb[base+ch];
  }
}

// ------- scan phase 3: recompute with real h0, reduce over s, fuse epilogue -------
__global__ void k_scan3(const u16* __restrict__ dt, const u16* __restrict__ xi,
                        const u16* __restrict__ bc, const u16* __restrict__ zs,
                        const float* __restrict__ alog, const float* __restrict__ Dp,
                        const float* __restrict__ Hin, u16* __restrict__ yss){
  // grid: B_ * NCH * (DI/16) = 1024 blocks of 256
  int blk = blockIdx.x;
  int dblk = blk & 7;
  int ch = (blk >> 3) & 15;
  int b = blk >> 7;
  int lane = threadIdx.x & 63;
  int wv = threadIdx.x >> 6;
  int s = lane & 15;
  int d = dblk*16 + wv*4 + (lane >> 4);
  float A = -__expf(alog[d*16+s]);
  float h = Hin[((b*128 + d)*16 + s)*16 + ch];
  float Dd = Dp[d];
  int pbase = b*4096 + ch*CHL;
  for(int i=0;i<CHL;i++){
    int p = pbase + i;
    float ldt = b2f(dt[(size_t)p*128 + d]);
    float lxi = b2f(xi[(size_t)p*128 + d]);
    float a = __expf(ldt*A);
    h = a*h + ldt*lxi*b2f(bc[(size_t)p*32 + s]);
    float contrib = h * b2f(bc[(size_t)p*32 + 16 + s]);
    contrib += __shfl_xor(contrib, 1);
    contrib += __shfl_xor(contrib, 2);
    contrib += __shfl_xor(contrib, 4);
    contrib += __shfl_xor(contrib, 8);
    if(s == 0){
      float zv = b2f(zs[(size_t)p*128 + d]);
      yss[(size_t)p*128 + d] = f2b((contrib + Dd*lxi) * zv);
    }
  }
}

extern "C" void kernel_launch(void* const* d_in, const int* in_sizes, int n_in,
                              void* d_out, int out_size, void* d_ws, size_t ws_size,
                              hipStream_t stream) {
  const float* x        = (const float*)d_in[0];
  const float* ln1_g    = (const float*)d_in[1];
  const float* ln1_b    = (const float*)d_in[2];
  const float* vin_w1   = (const float*)d_in[3];
  const float* vin_dw   = (const float*)d_in[4];
  const float* vin_w2   = (const float*)d_in[5];
  const float* vout_dw1 = (const float*)d_in[6];
  const float* vout_dw2 = (const float*)d_in[7];
  const float* ssm_in_w = (const float*)d_in[8];
  const float* ssm_cw   = (const float*)d_in[9];
  const float* ssm_cb   = (const float*)d_in[10];
  const float* ssm_xprj = (const float*)d_in[11];
  const float* ssm_dtw  = (const float*)d_in[12];
  const float* ssm_dtb  = (const float*)d_in[13];
  const float* ssm_Alog = (const float*)d_in[14];
  const float* ssm_D    = (const float*)d_in[15];
  const float* ssm_outw = (const float*)d_in[16];
  const float* ln2_g    = (const float*)d_in[17];
  const float* ln2_b    = (const float*)d_in[18];
  const float* ff_w1    = (const float*)d_in[19];
  const float* ff_dw    = (const float*)d_in[20];
  const float* ff_w2    = (const float*)d_in[21];
  float* out = (float*)d_out;

  // ---- 64MB bf16 arena with lifetime packing (units: bf16 elements) ----
  const size_t M = 1u<<20;
  u16* U   = (u16*)d_ws;
  u16* xT  = U;              // [0,2M)    lives to vision-out residual
  u16* tA  = U + 2*M;        // [2M,4M)
  u16* tB  = U + 4*M;        // [4M,6M)
  u16* x0  = U + 6*M;        // [6M,8M)   x0, later xR
  u16* xi  = U + 8*M;        // [8M,12M)  xi; first 2M later reused as y
  u16* zs  = U + 12*M;       // [12M,16M) silu(z)
  u16* xz  = U + 16*M;       // [16M,24M) xz; later t1; later fin (fp32)
  u16* dtb = U + 24*M;       // [24M,28M) dt; later start of t2
  u16* bc  = U + 28*M;       // [28M,29M)
  float* Pb  = (float*)(U + 29*M);
  float* Qb  = Pb + 256*1024;
  float* Hin = Qb + 256*1024;
  float* wf  = Hin + 256*1024;   // ends < 32M elems = 64MB total
  u16* yss = tA;             // 4M spanning tA+tB (both free during SSM)
  u16* y   = xi;             // 2M (xi free after scan3)
  u16* t2  = dtb;            // 8M [24M,32M) (scan scratch dead in FFN phase)
  float* fin = (float*)xz;   // 2M floats (t1 dead when ff2 runs)

  // --- vision in path ---
  k_trans_in<<<512,256,0,stream>>>(x, xT);
  k_ln<<<2048,256,0,stream>>>(xT, ln1_g, ln1_b, tA);
  k_mm<64,64,0,false><<<1024,256,0,stream>>>(vin_w1, 64, 0, tA, nullptr, nullptr, tB);
  k_dw3<64,2><<<8192,256,0,stream>>>(tB, vin_dw, nullptr, nullptr, tA);
  k_mm<64,64,0,false><<<1024,256,0,stream>>>(vin_w2, 64, 0, tA, nullptr, nullptr, x0);

  // --- SSM ---
  k_mm<64,256,0,false><<<1024,256,0,stream>>>(ssm_in_w, 256, 0, x0, nullptr, nullptr, xz);
  k_causal<<<16384,256,0,stream>>>(xz, ssm_cw, ssm_cb, xi, zs);
  k_fusew<<<64,256,0,stream>>>(ssm_xprj, ssm_dtw, wf);
  k_mm<128,128,2,false><<<1024,256,0,stream>>>(wf, 128, 0, xi, ssm_dtb, nullptr, dtb);
  k_mm<128,32,0,false><<<1024,256,0,stream>>>(ssm_xprj, 36, 4, xi, nullptr, nullptr, bc);
  k_scan1<<<1024,256,0,stream>>>(dtb, xi, bc, ssm_Alog, Pb, Qb);
  k_scan2<<<64,256,0,stream>>>(Pb, Qb, Hin);
  k_scan3<<<1024,256,0,stream>>>(dtb, xi, bc, zs, ssm_Alog, ssm_D, Hin, yss);
  k_mm<128,64,0,false><<<1024,256,0,stream>>>(ssm_outw, 64, 0, yss, nullptr, x0, y); // y = ssm + x0

  // --- vision out path:  xR = dw2(gelu(dw1(y))) + y + xT ---
  k_dw3<64,2><<<8192,256,0,stream>>>(y, vout_dw1, nullptr, nullptr, tA);
  k_dw3<64,0><<<8192,256,0,stream>>>(tA, vout_dw2, y, xT, x0);   // x0 now = xR

  // --- FFN ---
  k_ln<<<2048,256,0,stream>>>(x0, ln2_g, ln2_b, tB);
  k_mm<64,256,1,false><<<1024,256,0,stream>>>(ff_w1, 256, 0, tB, nullptr, nullptr, xz);  // t1
  k_dw3<256,1><<<32768,256,0,stream>>>(xz, ff_dw, nullptr, nullptr, t2);
  k_mm<256,64,0,true><<<1024,256,0,stream>>>(ff_w2, 64, 0, t2, nullptr, x0, fin);        // + xR

  k_trans_out<<<512,256,0,stream>>>(fin, out);
}

// Round 4
// 941.097 us; speedup vs baseline: 1.1726x; 1.1726x over previous
//
#include <hip/hip_runtime.h>
#include <hip/hip_bf16.h>
#include <math.h>

typedef unsigned short u16;   // bf16 storage

#define B_    8
#define C_    64
#define HW_   4096
#define NPIX  32768     // B_*HW_
#define DI    128
#define NCH   32
#define CHL   128       // HW_/NCH
#define TT    32        // timesteps staged per LDS tile

__device__ __forceinline__ float b2f(u16 v){ return __uint_as_float(((unsigned)v)<<16); }
__device__ __forceinline__ u16 f2b(float x){
  unsigned u = __float_as_uint(x);
  u += 0x7fff + ((u >> 16) & 1);      // RTNE
  return (u16)(u >> 16);
}
__device__ __forceinline__ float4 ld4b(const u16* p){
  ushort4 q = *(const ushort4*)p;
  return make_float4(b2f(q.x), b2f(q.y), b2f(q.z), b2f(q.w));
}
__device__ __forceinline__ float gelu_exact(float x){ return 0.5f*x*(1.0f+erff(x*0.70710678118654752f)); }
__device__ __forceinline__ float leaky02(float x){ return x>0.f ? x : 0.2f*x; }
__device__ __forceinline__ float softplus_(float x){ return fmaxf(x,0.f)+log1pf(__expf(-fabsf(x))); }
__device__ __forceinline__ float silu_(float x){ return x / (1.0f + __expf(-x)); }

// ---------------- NCHW fp32 -> NHWC bf16 ----------------
__global__ void k_trans_in(const float* __restrict__ x, u16* __restrict__ xT){
  __shared__ float tile[64][65];
  int blk = blockIdx.x;            // B_ * (HW_/64) = 512
  int b = blk >> 6;
  int hwb = (blk & 63) << 6;
  int lane = threadIdx.x & 63, row = threadIdx.x >> 6;
  const float* src = x + (size_t)b*C_*HW_;
  #pragma unroll
  for(int k=0;k<16;k++){
    int c = row + 4*k;
    tile[c][lane] = src[c*HW_ + hwb + lane];
  }
  __syncthreads();
  u16* dst = xT + (size_t)b*HW_*C_;
  #pragma unroll
  for(int k=0;k<16;k++){
    int hwl = row + 4*k;
    dst[(hwb+hwl)*C_ + lane] = f2b(tile[lane][hwl]);
  }
}

// ---------------- NHWC fp32 -> NCHW fp32 ----------------
__global__ void k_trans_out(const float* __restrict__ xO, float* __restrict__ out){
  __shared__ float tile[64][65];
  int blk = blockIdx.x;
  int b = blk >> 6;
  int hwb = (blk & 63) << 6;
  int lane = threadIdx.x & 63, row = threadIdx.x >> 6;
  const float* src = xO + (size_t)b*HW_*C_;
  #pragma unroll
  for(int k=0;k<16;k++){
    int hwl = row + 4*k;
    tile[lane][hwl] = src[(hwb+hwl)*C_ + lane];   // tile[c][hw_local]
  }
  __syncthreads();
  float* dst = out + (size_t)b*C_*HW_;
  #pragma unroll
  for(int k=0;k<16;k++){
    int c = row + 4*k;
    dst[c*HW_ + hwb + lane] = tile[c][lane];
  }
}

// ---------------- LayerNorm over c=64 (one wave per pixel) ----------------
__global__ void k_ln(const u16* __restrict__ in, const float* __restrict__ g,
                     const float* __restrict__ bta, u16* __restrict__ out){
  int wid = (blockIdx.x*blockDim.x + threadIdx.x) >> 6;
  int lane = threadIdx.x & 63;
  int nw = (gridDim.x*blockDim.x) >> 6;
  float gg = g[lane], bb = bta[lane];
  for(int p = wid; p < NPIX; p += nw){
    float v = b2f(in[(size_t)p*64 + lane]);
    float s = v, sq = v*v;
    #pragma unroll
    for(int o=32;o>0;o>>=1){ s += __shfl_xor(s,o); sq += __shfl_xor(sq,o); }
    float m = s*(1.f/64.f);
    float var = sq*(1.f/64.f) - m*m;
    float r = rsqrtf(var + 1e-5f);
    out[(size_t)p*64+lane] = f2b((v-m)*r*gg + bb);
  }
}

// ---------------- generic matmul: [NPIX,CIN](bf16) @ [CIN,COUT](fp32) ----------------
// ACT: 0 none, 1 leaky(0.2), 2 softplus (after bias)
template<int CIN, int COUT, int ACT, bool OUTF32>
__global__ void k_mm(const float* __restrict__ W, int ldw, int wofs,
                     const u16* __restrict__ in, const float* __restrict__ bias,
                     const u16* __restrict__ res, void* __restrict__ outv){
  __shared__ __align__(16) float WT[COUT*CIN];   // WT[d][(c+4d)%CIN]
  for(int idx = threadIdx.x; idx < CIN*COUT; idx += 256){
    int d = idx % COUT, c = idx / COUT;
    WT[d*CIN + ((c + 4*d) & (CIN-1))] = W[(size_t)c*ldw + wofs + d];
  }
  __syncthreads();
  const int PP = 256/COUT;          // pixels per pass
  int psub = threadIdx.x / COUT;
  int d = threadIdx.x % COUT;
  int rot = (4*d) & (CIN-1);
  const float* wrow = &WT[d*CIN];
  float bs = bias ? bias[d] : 0.f;
  int passes = NPIX/PP;
  for(int pass = blockIdx.x; pass < passes; pass += gridDim.x){
    int p = pass*PP + psub;
    float acc = 0.f;
    #pragma unroll 8
    for(int j=0;j<CIN;j+=4){
      float4 a = ld4b(in + (size_t)p*CIN + j);
      int cc = (j + rot) & (CIN-1);
      float4 w = *(const float4*)(wrow + cc);
      acc += a.x*w.x + a.y*w.y + a.z*w.z + a.w*w.w;
    }
    acc += bs;
    if(ACT==1) acc = leaky02(acc);
    else if(ACT==2) acc = softplus_(acc);
    if(res) acc += b2f(res[(size_t)p*COUT + d]);
    if(OUTF32) ((float*)outv)[(size_t)p*COUT + d] = acc;
    else       ((u16*)outv)[(size_t)p*COUT + d] = f2b(acc);
  }
}

// ---------------- depthwise 3x3 SAME, 4 channels per thread ----------------
template<int CN, int ACT>   // ACT: 0 none, 1 leaky, 2 gelu
__global__ void k_dw3(const u16* __restrict__ in, const float* __restrict__ wgt,
                      const u16* __restrict__ res1, const u16* __restrict__ res2,
                      u16* __restrict__ out){
  const int C4 = CN/4;
  int g = blockIdx.x*256 + threadIdx.x;     // NPIX*CN/4 threads
  int c4 = g % C4;
  int pix = g / C4;
  int w = pix & 63;
  int h = (pix >> 6) & 63;
  int b = pix >> 12;
  float a0=0.f, a1=0.f, a2=0.f, a3=0.f;
  #pragma unroll
  for(int kh=0;kh<3;kh++){
    int hh = h + kh - 1;
    if((unsigned)hh < 64u){
      #pragma unroll
      for(int kw=0;kw<3;kw++){
        int ww = w + kw - 1;
        if((unsigned)ww < 64u){
          ushort4 v = *(const ushort4*)(in + (size_t)((b*64+hh)*64 + ww)*CN + c4*4);
          float4 wv = *(const float4*)(wgt + (kh*3+kw)*CN + c4*4);
          a0 += b2f(v.x)*wv.x; a1 += b2f(v.y)*wv.y;
          a2 += b2f(v.z)*wv.z; a3 += b2f(v.w)*wv.w;
        }
      }
    }
  }
  if(ACT==1){ a0=leaky02(a0); a1=leaky02(a1); a2=leaky02(a2); a3=leaky02(a3); }
  else if(ACT==2){ a0=gelu_exact(a0); a1=gelu_exact(a1); a2=gelu_exact(a2); a3=gelu_exact(a3); }
  size_t ob = (size_t)pix*CN + c4*4;
  if(res1){ ushort4 r = *(const ushort4*)(res1 + ob);
            a0+=b2f(r.x); a1+=b2f(r.y); a2+=b2f(r.z); a3+=b2f(r.w); }
  if(res2){ ushort4 r = *(const ushort4*)(res2 + ob);
            a0+=b2f(r.x); a1+=b2f(r.y); a2+=b2f(r.z); a3+=b2f(r.w); }
  ushort4 o; o.x=f2b(a0); o.y=f2b(a1); o.z=f2b(a2); o.w=f2b(a3);
  *(ushort4*)(out + ob) = o;
}

// ---- causal depthwise conv1d (k=4) + silu, 4 d per thread; silu(z) extracted too ----
__global__ void k_causal(const u16* __restrict__ xz, const float* __restrict__ cw,
                         const float* __restrict__ cb, u16* __restrict__ xi,
                         u16* __restrict__ zs){
  int g = blockIdx.x*256 + threadIdx.x;     // NPIX*32 threads
  int d4 = g & 31;
  int p = g >> 5;            // b*4096 + t
  int t = p & 4095;
  float4 cbv = *(const float4*)(cb + d4*4);
  float a0=cbv.x, a1=cbv.y, a2=cbv.z, a3=cbv.w;
  #pragma unroll
  for(int k=0;k<4;k++){
    if(t + k - 3 >= 0){
      ushort4 v = *(const ushort4*)(xz + (size_t)(p + k - 3)*256 + d4*4);
      float4 wv = *(const float4*)(cw + k*128 + d4*4);
      a0 += b2f(v.x)*wv.x; a1 += b2f(v.y)*wv.y;
      a2 += b2f(v.z)*wv.z; a3 += b2f(v.w)*wv.w;
    }
  }
  ushort4 o; o.x=f2b(silu_(a0)); o.y=f2b(silu_(a1)); o.z=f2b(silu_(a2)); o.w=f2b(silu_(a3));
  *(ushort4*)(xi + (size_t)p*128 + d4*4) = o;
  ushort4 zv = *(const ushort4*)(xz + (size_t)p*256 + 128 + d4*4);
  ushort4 zo; zo.x=f2b(silu_(b2f(zv.x))); zo.y=f2b(silu_(b2f(zv.y)));
  zo.z=f2b(silu_(b2f(zv.z))); zo.w=f2b(silu_(b2f(zv.w)));
  *(ushort4*)(zs + (size_t)p*128 + d4*4) = zo;
}

// ---------------- fuse xproj[:, :4] @ dt_w  ->  Wf[128][128] fp32 ----------------
__global__ void k_fusew(const float* __restrict__ xproj, const float* __restrict__ dtw,
                        float* __restrict__ wf){
  int g = blockIdx.x*256 + threadIdx.x;     // 16384
  int d = g & 127;
  int c = g >> 7;
  float acc = 0.f;
  #pragma unroll
  for(int r=0;r<4;r++) acc += xproj[c*36 + r] * dtw[r*128 + d];
  wf[c*128 + d] = acc;
}

// ------- scan phase 1: thread owns (d, all 16 s) for one (b,chunk); LDS-staged -------
__global__ void k_scan1(const u16* __restrict__ dt, const u16* __restrict__ xi,
                        const u16* __restrict__ bc, const float* __restrict__ alog,
                        float* __restrict__ Pb, float* __restrict__ Qb){
  // grid: B_*NCH = 256 blocks of 128 threads (one per d)
  int blk = blockIdx.x;
  int ch = blk & (NCH-1);
  int b = blk >> 5;
  int d = threadIdx.x;
  __shared__ __align__(16) u16 sdt[TT*128], sxi[TT*128], sbc[TT*32];
  float A[16], P[16], Q[16];
  #pragma unroll
  for(int s=0;s<16;s++){ A[s] = -__expf(alog[d*16+s]); P[s]=1.f; Q[s]=0.f; }
  int pbase = b*HW_ + ch*CHL;
  for(int t0=0; t0<CHL; t0+=TT){
    __syncthreads();
    const uint4* gdt = (const uint4*)(dt + (size_t)(pbase+t0)*128);
    const uint4* gxi = (const uint4*)(xi + (size_t)(pbase+t0)*128);
    #pragma unroll
    for(int k=0;k<4;k++){
      ((uint4*)sdt)[d + 128*k] = gdt[d + 128*k];
      ((uint4*)sxi)[d + 128*k] = gxi[d + 128*k];
    }
    ((uint4*)sbc)[d] = ((const uint4*)(bc + (size_t)(pbase+t0)*32))[d];
    __syncthreads();
    for(int i=0;i<TT;i++){
      float dtv = b2f(sdt[i*128+d]);
      float u = dtv * b2f(sxi[i*128+d]);
      #pragma unroll
      for(int s=0;s<16;s++){
        float a = __expf(dtv*A[s]);
        P[s] *= a;
        Q[s] = a*Q[s] + u*b2f(sbc[i*32+s]);
      }
    }
  }
  int base = ((b*128+d)*16)*NCH + ch;
  #pragma unroll
  for(int s=0;s<16;s++){ Pb[base + s*NCH] = P[s]; Qb[base + s*NCH] = Q[s]; }
}

// ---------------- scan phase 2: sequential over 32 chunks ----------------
__global__ void k_scan2(const float* __restrict__ Pb, const float* __restrict__ Qb,
                        float* __restrict__ Hin){
  int g = blockIdx.x*256 + threadIdx.x;     // 16384 = (b,d,s)
  float h = 0.f;
  int base = g*NCH;
  #pragma unroll
  for(int ch=0; ch<NCH; ch++){
    Hin[base+ch] = h;
    h = Pb[base+ch]*h + Qb[base+ch];
  }
}

// ------- scan phase 3: recompute with real h0, s-reduction in registers, fused epilogue -------
__global__ void k_scan3(const u16* __restrict__ dt, const u16* __restrict__ xi,
                        const u16* __restrict__ bc, const u16* __restrict__ zs,
                        const float* __restrict__ alog, const float* __restrict__ Dp,
                        const float* __restrict__ Hin, u16* __restrict__ yss){
  int blk = blockIdx.x;         // 256 blocks of 128
  int ch = blk & (NCH-1);
  int b = blk >> 5;
  int d = threadIdx.x;
  __shared__ __align__(16) u16 sdt[TT*128], sxi[TT*128], szs[TT*128], sbc[TT*32];
  float A[16], h[16];
  int hb = ((b*128+d)*16)*NCH + ch;
  #pragma unroll
  for(int s=0;s<16;s++){ A[s] = -__expf(alog[d*16+s]); h[s] = Hin[hb + s*NCH]; }
  float Dd = Dp[d];
  int pbase = b*HW_ + ch*CHL;
  for(int t0=0; t0<CHL; t0+=TT){
    __syncthreads();
    const uint4* gdt = (const uint4*)(dt + (size_t)(pbase+t0)*128);
    const uint4* gxi = (const uint4*)(xi + (size_t)(pbase+t0)*128);
    const uint4* gzs = (const uint4*)(zs + (size_t)(pbase+t0)*128);
    #pragma unroll
    for(int k=0;k<4;k++){
      ((uint4*)sdt)[d + 128*k] = gdt[d + 128*k];
      ((uint4*)sxi)[d + 128*k] = gxi[d + 128*k];
      ((uint4*)szs)[d + 128*k] = gzs[d + 128*k];
    }
    ((uint4*)sbc)[d] = ((const uint4*)(bc + (size_t)(pbase+t0)*32))[d];
    __syncthreads();
    for(int i=0;i<TT;i++){
      float dtv = b2f(sdt[i*128+d]);
      float xiv = b2f(sxi[i*128+d]);
      float u = dtv*xiv;
      float acc = Dd*xiv;
      #pragma unroll
      for(int s=0;s<16;s++){
        float a = __expf(dtv*A[s]);
        h[s] = a*h[s] + u*b2f(sbc[i*32+s]);
        acc += h[s]*b2f(sbc[i*32+16+s]);
      }
      yss[(size_t)(pbase+t0+i)*128 + d] = f2b(acc * b2f(szs[i*128+d]));
    }
  }
}

extern "C" void kernel_launch(void* const* d_in, const int* in_sizes, int n_in,
                              void* d_out, int out_size, void* d_ws, size_t ws_size,
                              hipStream_t stream) {
  const float* x        = (const float*)d_in[0];
  const float* ln1_g    = (const float*)d_in[1];
  const float* ln1_b    = (const float*)d_in[2];
  const float* vin_w1   = (const float*)d_in[3];
  const float* vin_dw   = (const float*)d_in[4];
  const float* vin_w2   = (const float*)d_in[5];
  const float* vout_dw1 = (const float*)d_in[6];
  const float* vout_dw2 = (const float*)d_in[7];
  const float* ssm_in_w = (const float*)d_in[8];
  const float* ssm_cw   = (const float*)d_in[9];
  const float* ssm_cb   = (const float*)d_in[10];
  const float* ssm_xprj = (const float*)d_in[11];
  const float* ssm_dtw  = (const float*)d_in[12];
  const float* ssm_dtb  = (const float*)d_in[13];
  const float* ssm_Alog = (const float*)d_in[14];
  const float* ssm_D    = (const float*)d_in[15];
  const float* ssm_outw = (const float*)d_in[16];
  const float* ln2_g    = (const float*)d_in[17];
  const float* ln2_b    = (const float*)d_in[18];
  const float* ff_w1    = (const float*)d_in[19];
  const float* ff_dw    = (const float*)d_in[20];
  const float* ff_w2    = (const float*)d_in[21];
  float* out = (float*)d_out;

  // ---- bf16 arena, lifetime-packed (units: bf16 elements), ~64MB total ----
  const size_t M = 1u<<20;
  u16* U   = (u16*)d_ws;
  u16* xT  = U;              // [0,2M)    lives to vision-out residual
  u16* tA  = U + 2*M;        // [2M,4M)
  u16* tB  = U + 4*M;        // [4M,6M)
  u16* x0  = U + 6*M;        // [6M,8M)   x0, later xR
  u16* xi  = U + 8*M;        // [8M,12M)  xi; first 2M later reused as y
  u16* zs  = U + 12*M;       // [12M,16M) silu(z)
  u16* xz  = U + 16*M;       // [16M,24M) xz; dead after k_causal -> scan scratch; later fin
  u16* dtb = U + 24*M;       // [24M,28M) dt; later start of t2
  u16* bc  = U + 28*M;       // [28M,29M)
  // scan scratch lives in the dead xz region:
  float* Pb  = (float*)(U + 16*M);      // 512K floats [16M,18M)
  float* Qb  = (float*)(U + 18*M);      // 512K floats [18M,20M)
  float* Hin = (float*)(U + 20*M);      // 512K floats [20M,22M)
  float* wf  = (float*)(U + 22*M);      // 16K floats  [22M,22M+32K)
  u16* yss = tA;             // 4M spanning tA+tB (both free during SSM)
  u16* y   = xi;             // 2M (xi free after scan3)
  u16* t2  = dtb;            // 8M [24M,32M) (scan scratch dead in FFN phase)
  float* fin = (float*)(U + 16*M);   // 2M floats (scan scratch dead when ff2 runs)

  // --- vision in path ---
  k_trans_in<<<512,256,0,stream>>>(x, xT);
  k_ln<<<2048,256,0,stream>>>(xT, ln1_g, ln1_b, tA);
  k_mm<64,64,0,false><<<1024,256,0,stream>>>(vin_w1, 64, 0, tA, nullptr, nullptr, tB);
  k_dw3<64,2><<<2048,256,0,stream>>>(tB, vin_dw, nullptr, nullptr, tA);
  k_mm<64,64,0,false><<<1024,256,0,stream>>>(vin_w2, 64, 0, tA, nullptr, nullptr, x0);

  // --- SSM ---
  k_mm<64,256,0,false><<<1024,256,0,stream>>>(ssm_in_w, 256, 0, x0, nullptr, nullptr, xz);
  k_causal<<<4096,256,0,stream>>>(xz, ssm_cw, ssm_cb, xi, zs);
  k_fusew<<<64,256,0,stream>>>(ssm_xprj, ssm_dtw, wf);
  k_mm<128,128,2,false><<<1024,256,0,stream>>>(wf, 128, 0, xi, ssm_dtb, nullptr, dtb);
  k_mm<128,32,0,false><<<1024,256,0,stream>>>(ssm_xprj, 36, 4, xi, nullptr, nullptr, bc);
  k_scan1<<<256,128,0,stream>>>(dtb, xi, bc, ssm_Alog, Pb, Qb);
  k_scan2<<<64,256,0,stream>>>(Pb, Qb, Hin);
  k_scan3<<<256,128,0,stream>>>(dtb, xi, bc, zs, ssm_Alog, ssm_D, Hin, yss);
  k_mm<128,64,0,false><<<1024,256,0,stream>>>(ssm_outw, 64, 0, yss, nullptr, x0, y); // y = ssm + x0

  // --- vision out path:  xR = dw2(gelu(dw1(y))) + y + xT ---
  k_dw3<64,2><<<2048,256,0,stream>>>(y, vout_dw1, nullptr, nullptr, tA);
  k_dw3<64,0><<<2048,256,0,stream>>>(tA, vout_dw2, y, xT, x0);   // x0 now = xR

  // --- FFN ---
  k_ln<<<2048,256,0,stream>>>(x0, ln2_g, ln2_b, tB);
  k_mm<64,256,1,false><<<1024,256,0,stream>>>(ff_w1, 256, 0, tB, nullptr, nullptr, xz);  // t1
  k_dw3<256,1><<<8192,256,0,stream>>>(xz, ff_dw, nullptr, nullptr, t2);
  k_mm<256,64,0,true><<<1024,256,0,stream>>>(ff_w2, 64, 0, t2, nullptr, x0, fin);        // + xR

  k_trans_out<<<512,256,0,stream>>>(fin, out);
}

// Round 5
// 407.955 us; speedup vs baseline: 2.7051x; 2.3069x over previous
//
#include <hip/hip_runtime.h>
#include <hip/hip_bf16.h>
#include <math.h>

typedef unsigned short u16;   // bf16 storage
typedef __attribute__((ext_vector_type(8))) short s8v;    // 8 bf16 = 4 VGPR
typedef __attribute__((ext_vector_type(4))) float f4v;    // MFMA acc

#define B_    8
#define C_    64
#define HW_   4096
#define NPIX  32768     // B_*HW_
#define DI    128
#define NCH   32
#define CHL   128       // HW_/NCH
#define TT    32        // timesteps staged per LDS tile

__device__ __forceinline__ float b2f(u16 v){ return __uint_as_float(((unsigned)v)<<16); }
__device__ __forceinline__ u16 f2b(float x){
  unsigned u = __float_as_uint(x);
  u += 0x7fff + ((u >> 16) & 1);      // RTNE
  return (u16)(u >> 16);
}
__device__ __forceinline__ float gelu_exact(float x){ return 0.5f*x*(1.0f+erff(x*0.70710678118654752f)); }
__device__ __forceinline__ float leaky02(float x){ return x>0.f ? x : 0.2f*x; }
__device__ __forceinline__ float softplus_(float x){ return fmaxf(x,0.f)+log1pf(__expf(-fabsf(x))); }
__device__ __forceinline__ float silu_(float x){ return x / (1.0f + __expf(-x)); }

// ---------------- NCHW fp32 -> NHWC bf16 ----------------
__global__ void k_trans_in(const float* __restrict__ x, u16* __restrict__ xT){
  __shared__ float tile[64][65];
  int blk = blockIdx.x;            // B_ * (HW_/64) = 512
  int b = blk >> 6;
  int hwb = (blk & 63) << 6;
  int lane = threadIdx.x & 63, row = threadIdx.x >> 6;
  const float* src = x + (size_t)b*C_*HW_;
  #pragma unroll
  for(int k=0;k<16;k++){
    int c = row + 4*k;
    tile[c][lane] = src[c*HW_ + hwb + lane];
  }
  __syncthreads();
  u16* dst = xT + (size_t)b*HW_*C_;
  #pragma unroll
  for(int k=0;k<16;k++){
    int hwl = row + 4*k;
    dst[(hwb+hwl)*C_ + lane] = f2b(tile[lane][hwl]);
  }
}

// ---------------- NHWC fp32 -> NCHW fp32 ----------------
__global__ void k_trans_out(const float* __restrict__ xO, float* __restrict__ out){
  __shared__ float tile[64][65];
  int blk = blockIdx.x;
  int b = blk >> 6;
  int hwb = (blk & 63) << 6;
  int lane = threadIdx.x & 63, row = threadIdx.x >> 6;
  const float* src = xO + (size_t)b*HW_*C_;
  #pragma unroll
  for(int k=0;k<16;k++){
    int hwl = row + 4*k;
    tile[lane][hwl] = src[(hwb+hwl)*C_ + lane];   // tile[c][hw_local]
  }
  __syncthreads();
  float* dst = out + (size_t)b*C_*HW_;
  #pragma unroll
  for(int k=0;k<16;k++){
    int c = row + 4*k;
    dst[c*HW_ + hwb + lane] = tile[c][lane];
  }
}

// ---------------- LayerNorm over c=64 (one wave per pixel) ----------------
__global__ void k_ln(const u16* __restrict__ in, const float* __restrict__ g,
                     const float* __restrict__ bta, u16* __restrict__ out){
  int wid = (blockIdx.x*blockDim.x + threadIdx.x) >> 6;
  int lane = threadIdx.x & 63;
  int nw = (gridDim.x*blockDim.x) >> 6;
  float gg = g[lane], bb = bta[lane];
  for(int p = wid; p < NPIX; p += nw){
    float v = b2f(in[(size_t)p*64 + lane]);
    float s = v, sq = v*v;
    #pragma unroll
    for(int o=32;o>0;o>>=1){ s += __shfl_xor(s,o); sq += __shfl_xor(sq,o); }
    float m = s*(1.f/64.f);
    float var = sq*(1.f/64.f) - m*m;
    float r = rsqrtf(var + 1e-5f);
    out[(size_t)p*64+lane] = f2b((v-m)*r*gg + bb);
  }
}

// ========== MFMA matmul: [NPIX,CIN](bf16) @ [CIN,COUT](fp32->bf16) ==========
// ACT: 0 none, 1 leaky(0.2), 2 softplus(after bias). Residual added after act.
// Block: 256 thr / 4 waves; 64 pixels per block; wave w owns m-frag w (16 rows),
// loops all COUT/16 n-strips. K chunked at 128 to bound LDS. Weight staged
// transposed WT[n][k] bf16 with +8 pad (conflict-free ds_read_b128 frags).
template<int CIN, int COUT, int ACT, bool OUTF32>
__global__ __launch_bounds__(256) void k_mfma(const float* __restrict__ W, int ldw, int wofs,
                     const u16* __restrict__ in, const float* __restrict__ bias,
                     const u16* __restrict__ res, void* __restrict__ outv){
  const int KCH = (CIN < 128) ? CIN : 128;
  const int LDA = KCH + 8;            // u16 units; keeps rows 16B-aligned
  const int NS  = COUT / 16;
  __shared__ __align__(16) u16 sA[64*LDA];
  __shared__ __align__(16) u16 sW[COUT*LDA];
  int tid = threadIdx.x;
  int p0 = blockIdx.x * 64;
  int ln = tid & 63, wv = tid >> 6;
  int mrow = ln & 15, quad = ln >> 4;
  f4v acc[NS];
  #pragma unroll
  for(int i=0;i<NS;i++) acc[i] = (f4v){0.f,0.f,0.f,0.f};
  const u16* aBase = sA + (wv*16 + mrow)*LDA + quad*8;
  const u16* wBase = sW + mrow*LDA + quad*8;
  for(int k0=0; k0<CIN; k0+=KCH){
    if(k0) __syncthreads();
    // stage W chunk, transposed + bf16-cast
    for(int idx=tid; idx<KCH*COUT; idx+=256){
      int c = idx / COUT, n = idx % COUT;
      sW[n*LDA + c] = f2b(W[(size_t)(k0+c)*ldw + wofs + n]);
    }
    // stage A chunk (uint4 = 8 bf16)
    const int RW = KCH/8;
    for(int g=tid; g<64*RW; g+=256){
      int row = g / RW, c8 = (g % RW)*8;
      *(uint4*)(sA + row*LDA + c8) = *(const uint4*)(in + (size_t)(p0+row)*CIN + k0 + c8);
    }
    __syncthreads();
    #pragma unroll
    for(int kk=0; kk<KCH; kk+=32){
      s8v af = *(const s8v*)(aBase + kk);
      #pragma unroll
      for(int ns=0; ns<NS; ns++){
        s8v bf = *(const s8v*)(wBase + ns*16*LDA + kk);
        acc[ns] = __builtin_amdgcn_mfma_f32_16x16x32_bf16(af, bf, acc[ns], 0, 0, 0);
      }
    }
  }
  // epilogue: C/D layout col=lane&15 (n), row=quad*4+reg (m)
  int pr = p0 + wv*16 + quad*4;
  #pragma unroll
  for(int ns=0; ns<NS; ns++){
    int n = ns*16 + mrow;
    float bs = bias ? bias[n] : 0.f;
    #pragma unroll
    for(int r=0;r<4;r++){
      float v = acc[ns][r] + bs;
      if(ACT==1) v = leaky02(v);
      else if(ACT==2) v = softplus_(v);
      if(res) v += b2f(res[(size_t)(pr+r)*COUT + n]);
      if(OUTF32) ((float*)outv)[(size_t)(pr+r)*COUT + n] = v;
      else       ((u16*)outv)[(size_t)(pr+r)*COUT + n] = f2b(v);
    }
  }
}

// ---------------- depthwise 3x3 SAME, 4 channels per thread ----------------
template<int CN, int ACT>   // ACT: 0 none, 1 leaky, 2 gelu
__global__ void k_dw3(const u16* __restrict__ in, const float* __restrict__ wgt,
                      const u16* __restrict__ res1, const u16* __restrict__ res2,
                      u16* __restrict__ out){
  const int C4 = CN/4;
  int g = blockIdx.x*256 + threadIdx.x;     // NPIX*CN/4 threads
  int c4 = g % C4;
  int pix = g / C4;
  int w = pix & 63;
  int h = (pix >> 6) & 63;
  int b = pix >> 12;
  float a0=0.f, a1=0.f, a2=0.f, a3=0.f;
  #pragma unroll
  for(int kh=0;kh<3;kh++){
    int hh = h + kh - 1;
    if((unsigned)hh < 64u){
      #pragma unroll
      for(int kw=0;kw<3;kw++){
        int ww = w + kw - 1;
        if((unsigned)ww < 64u){
          ushort4 v = *(const ushort4*)(in + (size_t)((b*64+hh)*64 + ww)*CN + c4*4);
          float4 wv = *(const float4*)(wgt + (kh*3+kw)*CN + c4*4);
          a0 += b2f(v.x)*wv.x; a1 += b2f(v.y)*wv.y;
          a2 += b2f(v.z)*wv.z; a3 += b2f(v.w)*wv.w;
        }
      }
    }
  }
  if(ACT==1){ a0=leaky02(a0); a1=leaky02(a1); a2=leaky02(a2); a3=leaky02(a3); }
  else if(ACT==2){ a0=gelu_exact(a0); a1=gelu_exact(a1); a2=gelu_exact(a2); a3=gelu_exact(a3); }
  size_t ob = (size_t)pix*CN + c4*4;
  if(res1){ ushort4 r = *(const ushort4*)(res1 + ob);
            a0+=b2f(r.x); a1+=b2f(r.y); a2+=b2f(r.z); a3+=b2f(r.w); }
  if(res2){ ushort4 r = *(const ushort4*)(res2 + ob);
            a0+=b2f(r.x); a1+=b2f(r.y); a2+=b2f(r.z); a3+=b2f(r.w); }
  ushort4 o; o.x=f2b(a0); o.y=f2b(a1); o.z=f2b(a2); o.w=f2b(a3);
  *(ushort4*)(out + ob) = o;
}

// ---- causal depthwise conv1d (k=4) + silu, 4 d per thread; silu(z) extracted too ----
__global__ void k_causal(const u16* __restrict__ xz, const float* __restrict__ cw,
                         const float* __restrict__ cb, u16* __restrict__ xi,
                         u16* __restrict__ zs){
  int g = blockIdx.x*256 + threadIdx.x;     // NPIX*32 threads
  int d4 = g & 31;
  int p = g >> 5;            // b*4096 + t
  int t = p & 4095;
  float4 cbv = *(const float4*)(cb + d4*4);
  float a0=cbv.x, a1=cbv.y, a2=cbv.z, a3=cbv.w;
  #pragma unroll
  for(int k=0;k<4;k++){
    if(t + k - 3 >= 0){
      ushort4 v = *(const ushort4*)(xz + (size_t)(p + k - 3)*256 + d4*4);
      float4 wv = *(const float4*)(cw + k*128 + d4*4);
      a0 += b2f(v.x)*wv.x; a1 += b2f(v.y)*wv.y;
      a2 += b2f(v.z)*wv.z; a3 += b2f(v.w)*wv.w;
    }
  }
  ushort4 o; o.x=f2b(silu_(a0)); o.y=f2b(silu_(a1)); o.z=f2b(silu_(a2)); o.w=f2b(silu_(a3));
  *(ushort4*)(xi + (size_t)p*128 + d4*4) = o;
  ushort4 zv = *(const ushort4*)(xz + (size_t)p*256 + 128 + d4*4);
  ushort4 zo; zo.x=f2b(silu_(b2f(zv.x))); zo.y=f2b(silu_(b2f(zv.y)));
  zo.z=f2b(silu_(b2f(zv.z))); zo.w=f2b(silu_(b2f(zv.w)));
  *(ushort4*)(zs + (size_t)p*128 + d4*4) = zo;
}

// ---------------- fuse xproj[:, :4] @ dt_w  ->  Wf[128][128] fp32 ----------------
__global__ void k_fusew(const float* __restrict__ xproj, const float* __restrict__ dtw,
                        float* __restrict__ wf){
  int g = blockIdx.x*256 + threadIdx.x;     // 16384
  int d = g & 127;
  int c = g >> 7;
  float acc = 0.f;
  #pragma unroll
  for(int r=0;r<4;r++) acc += xproj[c*36 + r] * dtw[r*128 + d];
  wf[c*128 + d] = acc;
}

// ------- scan phase 1: thread owns (d, all 16 s) for one (b,chunk); LDS-staged -------
__global__ void k_scan1(const u16* __restrict__ dt, const u16* __restrict__ xi,
                        const u16* __restrict__ bc, const float* __restrict__ alog,
                        float* __restrict__ Pb, float* __restrict__ Qb){
  // grid: B_*NCH = 256 blocks of 128 threads (one per d)
  int blk = blockIdx.x;
  int ch = blk & (NCH-1);
  int b = blk >> 5;
  int d = threadIdx.x;
  __shared__ __align__(16) u16 sdt[TT*128], sxi[TT*128], sbc[TT*32];
  float A[16], P[16], Q[16];
  #pragma unroll
  for(int s=0;s<16;s++){ A[s] = -__expf(alog[d*16+s]); P[s]=1.f; Q[s]=0.f; }
  int pbase = b*HW_ + ch*CHL;
  for(int t0=0; t0<CHL; t0+=TT){
    __syncthreads();
    const uint4* gdt = (const uint4*)(dt + (size_t)(pbase+t0)*128);
    const uint4* gxi = (const uint4*)(xi + (size_t)(pbase+t0)*128);
    #pragma unroll
    for(int k=0;k<4;k++){
      ((uint4*)sdt)[d + 128*k] = gdt[d + 128*k];
      ((uint4*)sxi)[d + 128*k] = gxi[d + 128*k];
    }
    ((uint4*)sbc)[d] = ((const uint4*)(bc + (size_t)(pbase+t0)*32))[d];
    __syncthreads();
    for(int i=0;i<TT;i++){
      float dtv = b2f(sdt[i*128+d]);
      float u = dtv * b2f(sxi[i*128+d]);
      #pragma unroll
      for(int s=0;s<16;s++){
        float a = __expf(dtv*A[s]);
        P[s] *= a;
        Q[s] = a*Q[s] + u*b2f(sbc[i*32+s]);
      }
    }
  }
  int base = ((b*128+d)*16)*NCH + ch;
  #pragma unroll
  for(int s=0;s<16;s++){ Pb[base + s*NCH] = P[s]; Qb[base + s*NCH] = Q[s]; }
}

// ---------------- scan phase 2: sequential over 32 chunks ----------------
__global__ void k_scan2(const float* __restrict__ Pb, const float* __restrict__ Qb,
                        float* __restrict__ Hin){
  int g = blockIdx.x*256 + threadIdx.x;     // 16384 = (b,d,s)
  float h = 0.f;
  int base = g*NCH;
  #pragma unroll
  for(int ch=0; ch<NCH; ch++){
    Hin[base+ch] = h;
    h = Pb[base+ch]*h + Qb[base+ch];
  }
}

// ------- scan phase 3: recompute with real h0, s-reduction in registers, fused epilogue -------
__global__ void k_scan3(const u16* __restrict__ dt, const u16* __restrict__ xi,
                        const u16* __restrict__ bc, const u16* __restrict__ zs,
                        const float* __restrict__ alog, const float* __restrict__ Dp,
                        const float* __restrict__ Hin, u16* __restrict__ yss){
  int blk = blockIdx.x;         // 256 blocks of 128
  int ch = blk & (NCH-1);
  int b = blk >> 5;
  int d = threadIdx.x;
  __shared__ __align__(16) u16 sdt[TT*128], sxi[TT*128], szs[TT*128], sbc[TT*32];
  float A[16], h[16];
  int hb = ((b*128+d)*16)*NCH + ch;
  #pragma unroll
  for(int s=0;s<16;s++){ A[s] = -__expf(alog[d*16+s]); h[s] = Hin[hb + s*NCH]; }
  float Dd = Dp[d];
  int pbase = b*HW_ + ch*CHL;
  for(int t0=0; t0<CHL; t0+=TT){
    __syncthreads();
    const uint4* gdt = (const uint4*)(dt + (size_t)(pbase+t0)*128);
    const uint4* gxi = (const uint4*)(xi + (size_t)(pbase+t0)*128);
    const uint4* gzs = (const uint4*)(zs + (size_t)(pbase+t0)*128);
    #pragma unroll
    for(int k=0;k<4;k++){
      ((uint4*)sdt)[d + 128*k] = gdt[d + 128*k];
      ((uint4*)sxi)[d + 128*k] = gxi[d + 128*k];
      ((uint4*)szs)[d + 128*k] = gzs[d + 128*k];
    }
    ((uint4*)sbc)[d] = ((const uint4*)(bc + (size_t)(pbase+t0)*32))[d];
    __syncthreads();
    for(int i=0;i<TT;i++){
      float dtv = b2f(sdt[i*128+d]);
      float xiv = b2f(sxi[i*128+d]);
      float u = dtv*xiv;
      float acc = Dd*xiv;
      #pragma unroll
      for(int s=0;s<16;s++){
        float a = __expf(dtv*A[s]);
        h[s] = a*h[s] + u*b2f(sbc[i*32+s]);
        acc += h[s]*b2f(sbc[i*32+16+s]);
      }
      yss[(size_t)(pbase+t0+i)*128 + d] = f2b(acc * b2f(szs[i*128+d]));
    }
  }
}

extern "C" void kernel_launch(void* const* d_in, const int* in_sizes, int n_in,
                              void* d_out, int out_size, void* d_ws, size_t ws_size,
                              hipStream_t stream) {
  const float* x        = (const float*)d_in[0];
  const float* ln1_g    = (const float*)d_in[1];
  const float* ln1_b    = (const float*)d_in[2];
  const float* vin_w1   = (const float*)d_in[3];
  const float* vin_dw   = (const float*)d_in[4];
  const float* vin_w2   = (const float*)d_in[5];
  const float* vout_dw1 = (const float*)d_in[6];
  const float* vout_dw2 = (const float*)d_in[7];
  const float* ssm_in_w = (const float*)d_in[8];
  const float* ssm_cw   = (const float*)d_in[9];
  const float* ssm_cb   = (const float*)d_in[10];
  const float* ssm_xprj = (const float*)d_in[11];
  const float* ssm_dtw  = (const float*)d_in[12];
  const float* ssm_dtb  = (const float*)d_in[13];
  const float* ssm_Alog = (const float*)d_in[14];
  const float* ssm_D    = (const float*)d_in[15];
  const float* ssm_outw = (const float*)d_in[16];
  const float* ln2_g    = (const float*)d_in[17];
  const float* ln2_b    = (const float*)d_in[18];
  const float* ff_w1    = (const float*)d_in[19];
  const float* ff_dw    = (const float*)d_in[20];
  const float* ff_w2    = (const float*)d_in[21];
  float* out = (float*)d_out;

  // ---- bf16 arena, lifetime-packed (units: bf16 elements), ~64MB total ----
  const size_t M = 1u<<20;
  u16* U   = (u16*)d_ws;
  u16* xT  = U;              // [0,2M)    lives to vision-out residual
  u16* tA  = U + 2*M;        // [2M,4M)
  u16* tB  = U + 4*M;        // [4M,6M)
  u16* x0  = U + 6*M;        // [6M,8M)   x0, later xR
  u16* xi  = U + 8*M;        // [8M,12M)  xi; first 2M later reused as y
  u16* zs  = U + 12*M;       // [12M,16M) silu(z)
  u16* xz  = U + 16*M;       // [16M,24M) xz; dead after k_causal -> scan scratch; later fin
  u16* dtb = U + 24*M;       // [24M,28M) dt; later start of t2
  u16* bc  = U + 28*M;       // [28M,29M)
  // scan scratch lives in the dead xz region:
  float* Pb  = (float*)(U + 16*M);      // 512K floats [16M,18M)
  float* Qb  = (float*)(U + 18*M);      // 512K floats [18M,20M)
  float* Hin = (float*)(U + 20*M);      // 512K floats [20M,22M)
  float* wf  = (float*)(U + 22*M);      // 16K floats  [22M,22M+32K)
  u16* yss = tA;             // 4M spanning tA+tB (both free during SSM)
  u16* y   = xi;             // 2M (xi free after scan3)
  u16* t2  = dtb;            // 8M [24M,32M) (scan scratch dead in FFN phase)
  float* fin = (float*)(U + 16*M);   // 2M floats (scan scratch dead when ff2 runs)

  // --- vision in path ---
  k_trans_in<<<512,256,0,stream>>>(x, xT);
  k_ln<<<2048,256,0,stream>>>(xT, ln1_g, ln1_b, tA);
  k_mfma<64,64,0,false><<<512,256,0,stream>>>(vin_w1, 64, 0, tA, nullptr, nullptr, tB);
  k_dw3<64,2><<<2048,256,0,stream>>>(tB, vin_dw, nullptr, nullptr, tA);
  k_mfma<64,64,0,false><<<512,256,0,stream>>>(vin_w2, 64, 0, tA, nullptr, nullptr, x0);

  // --- SSM ---
  k_mfma<64,256,0,false><<<512,256,0,stream>>>(ssm_in_w, 256, 0, x0, nullptr, nullptr, xz);
  k_causal<<<4096,256,0,stream>>>(xz, ssm_cw, ssm_cb, xi, zs);
  k_fusew<<<64,256,0,stream>>>(ssm_xprj, ssm_dtw, wf);
  k_mfma<128,128,2,false><<<512,256,0,stream>>>(wf, 128, 0, xi, ssm_dtb, nullptr, dtb);
  k_mfma<128,32,0,false><<<512,256,0,stream>>>(ssm_xprj, 36, 4, xi, nullptr, nullptr, bc);
  k_scan1<<<256,128,0,stream>>>(dtb, xi, bc, ssm_Alog, Pb, Qb);
  k_scan2<<<64,256,0,stream>>>(Pb, Qb, Hin);
  k_scan3<<<256,128,0,stream>>>(dtb, xi, bc, zs, ssm_Alog, ssm_D, Hin, yss);
  k_mfma<128,64,0,false><<<512,256,0,stream>>>(ssm_outw, 64, 0, yss, nullptr, x0, y); // y = ssm + x0

  // --- vision out path:  xR = dw2(gelu(dw1(y))) + y + xT ---
  k_dw3<64,2><<<2048,256,0,stream>>>(y, vout_dw1, nullptr, nullptr, tA);
  k_dw3<64,0><<<2048,256,0,stream>>>(tA, vout_dw2, y, xT, x0);   // x0 now = xR

  // --- FFN ---
  k_ln<<<2048,256,0,stream>>>(x0, ln2_g, ln2_b, tB);
  k_mfma<64,256,1,false><<<512,256,0,stream>>>(ff_w1, 256, 0, tB, nullptr, nullptr, xz);  // t1
  k_dw3<256,1><<<8192,256,0,stream>>>(xz, ff_dw, nullptr, nullptr, t2);
  k_mfma<256,64,0,true><<<512,256,0,stream>>>(ff_w2, 64, 0, t2, nullptr, x0, fin);        // + xR

  k_trans_out<<<512,256,0,stream>>>(fin, out);
}

// Round 6
// 348.777 us; speedup vs baseline: 3.1641x; 1.1697x over previous
//
#include <hip/hip_runtime.h>
#include <hip/hip_bf16.h>
#include <math.h>

typedef unsigned short u16;   // bf16 storage
typedef __attribute__((ext_vector_type(8))) short s8v;    // 8 bf16 = 4 VGPR
typedef __attribute__((ext_vector_type(4))) float f4v;    // MFMA acc

#define B_    8
#define C_    64
#define HW_   4096
#define NPIX  32768     // B_*HW_
#define DI    128
#define NCH   256
#define CHL   16        // HW_/NCH

__device__ __forceinline__ float b2f(u16 v){ return __uint_as_float(((unsigned)v)<<16); }
__device__ __forceinline__ u16 f2b(float x){
  unsigned u = __float_as_uint(x);
  u += 0x7fff + ((u >> 16) & 1);      // RTNE
  return (u16)(u >> 16);
}
__device__ __forceinline__ float gelu_exact(float x){ return 0.5f*x*(1.0f+erff(x*0.70710678118654752f)); }
__device__ __forceinline__ float leaky02(float x){ return x>0.f ? x : 0.2f*x; }
__device__ __forceinline__ float softplus_(float x){ return fmaxf(x,0.f)+log1pf(__expf(-fabsf(x))); }
__device__ __forceinline__ float silu_(float x){ return x / (1.0f + __expf(-x)); }

// ---------------- NCHW fp32 -> NHWC bf16 ----------------
__global__ void k_trans_in(const float* __restrict__ x, u16* __restrict__ xT){
  __shared__ float tile[64][65];
  int blk = blockIdx.x;            // B_ * (HW_/64) = 512
  int b = blk >> 6;
  int hwb = (blk & 63) << 6;
  int lane = threadIdx.x & 63, row = threadIdx.x >> 6;
  const float* src = x + (size_t)b*C_*HW_;
  #pragma unroll
  for(int k=0;k<16;k++){
    int c = row + 4*k;
    tile[c][lane] = src[c*HW_ + hwb + lane];
  }
  __syncthreads();
  u16* dst = xT + (size_t)b*HW_*C_;
  #pragma unroll
  for(int k=0;k<16;k++){
    int hwl = row + 4*k;
    dst[(hwb+hwl)*C_ + lane] = f2b(tile[lane][hwl]);
  }
}

// ---------------- NHWC fp32 -> NCHW fp32 ----------------
__global__ void k_trans_out(const float* __restrict__ xO, float* __restrict__ out){
  __shared__ float tile[64][65];
  int blk = blockIdx.x;
  int b = blk >> 6;
  int hwb = (blk & 63) << 6;
  int lane = threadIdx.x & 63, row = threadIdx.x >> 6;
  const float* src = xO + (size_t)b*HW_*C_;
  #pragma unroll
  for(int k=0;k<16;k++){
    int hwl = row + 4*k;
    tile[lane][hwl] = src[(hwb+hwl)*C_ + lane];
  }
  __syncthreads();
  float* dst = out + (size_t)b*C_*HW_;
  #pragma unroll
  for(int k=0;k<16;k++){
    int c = row + 4*k;
    dst[c*HW_ + hwb + lane] = tile[c][lane];
  }
}

// ---------------- LayerNorm over c=64 (one wave per pixel) ----------------
__global__ void k_ln(const u16* __restrict__ in, const float* __restrict__ g,
                     const float* __restrict__ bta, u16* __restrict__ out){
  int wid = (blockIdx.x*blockDim.x + threadIdx.x) >> 6;
  int lane = threadIdx.x & 63;
  int nw = (gridDim.x*blockDim.x) >> 6;
  float gg = g[lane], bb = bta[lane];
  for(int p = wid; p < NPIX; p += nw){
    float v = b2f(in[(size_t)p*64 + lane]);
    float s = v, sq = v*v;
    #pragma unroll
    for(int o=32;o>0;o>>=1){ s += __shfl_xor(s,o); sq += __shfl_xor(sq,o); }
    float m = s*(1.f/64.f);
    float var = sq*(1.f/64.f) - m*m;
    float r = rsqrtf(var + 1e-5f);
    out[(size_t)p*64+lane] = f2b((v-m)*r*gg + bb);
  }
}

// ========== MFMA matmul: [NPIX,CIN](bf16) @ [CIN,COUT](fp32->bf16) ==========
template<int CIN, int COUT, int ACT, bool OUTF32>
__global__ __launch_bounds__(256) void k_mfma(const float* __restrict__ W, int ldw, int wofs,
                     const u16* __restrict__ in, const float* __restrict__ bias,
                     const u16* __restrict__ res, void* __restrict__ outv){
  const int KCH = (CIN < 128) ? CIN : 128;
  const int LDA = KCH + 8;            // u16 units
  const int NS  = COUT / 16;
  __shared__ __align__(16) u16 sA[64*LDA];
  __shared__ __align__(16) u16 sW[COUT*LDA];
  int tid = threadIdx.x;
  int p0 = blockIdx.x * 64;
  int ln = tid & 63, wv = tid >> 6;
  int mrow = ln & 15, quad = ln >> 4;
  f4v acc[NS];
  #pragma unroll
  for(int i=0;i<NS;i++) acc[i] = (f4v){0.f,0.f,0.f,0.f};
  const u16* aBase = sA + (wv*16 + mrow)*LDA + quad*8;
  const u16* wBase = sW + mrow*LDA + quad*8;
  for(int k0=0; k0<CIN; k0+=KCH){
    if(k0) __syncthreads();
    // stage W chunk, transposed + bf16-cast (float4 along n)
    for(int idx=tid*4; idx<KCH*COUT; idx+=1024){
      int c = idx / COUT, n = idx % COUT;
      float4 w = *(const float4*)(&W[(size_t)(k0+c)*ldw + wofs + n]);
      u16* dst = sW + n*LDA + c;
      dst[0]=f2b(w.x); dst[LDA]=f2b(w.y); dst[2*LDA]=f2b(w.z); dst[3*LDA]=f2b(w.w);
    }
    // stage A chunk (uint4 = 8 bf16)
    const int RW = KCH/8;
    for(int g=tid; g<64*RW; g+=256){
      int row = g / RW, c8 = (g % RW)*8;
      *(uint4*)(sA + row*LDA + c8) = *(const uint4*)(in + (size_t)(p0+row)*CIN + k0 + c8);
    }
    __syncthreads();
    #pragma unroll
    for(int kk=0; kk<KCH; kk+=32){
      s8v af = *(const s8v*)(aBase + kk);
      #pragma unroll
      for(int ns=0; ns<NS; ns++){
        s8v bf = *(const s8v*)(wBase + ns*16*LDA + kk);
        acc[ns] = __builtin_amdgcn_mfma_f32_16x16x32_bf16(af, bf, acc[ns], 0, 0, 0);
      }
    }
  }
  int pr = p0 + wv*16 + quad*4;
  #pragma unroll
  for(int ns=0; ns<NS; ns++){
    int n = ns*16 + mrow;
    float bs = bias ? bias[n] : 0.f;
    #pragma unroll
    for(int r=0;r<4;r++){
      float v = acc[ns][r] + bs;
      if(ACT==1) v = leaky02(v);
      else if(ACT==2) v = softplus_(v);
      if(res) v += b2f(res[(size_t)(pr+r)*COUT + n]);
      if(OUTF32) ((float*)outv)[(size_t)(pr+r)*COUT + n] = v;
      else       ((u16*)outv)[(size_t)(pr+r)*COUT + n] = f2b(v);
    }
  }
}

// ---------------- depthwise 3x3 SAME, 4 channels per thread ----------------
template<int CN, int ACT>   // ACT: 0 none, 1 leaky, 2 gelu
__global__ void k_dw3(const u16* __restrict__ in, const float* __restrict__ wgt,
                      const u16* __restrict__ res1, const u16* __restrict__ res2,
                      u16* __restrict__ out){
  const int C4 = CN/4;
  int g = blockIdx.x*256 + threadIdx.x;
  int c4 = g % C4;
  int pix = g / C4;
  int w = pix & 63;
  int h = (pix >> 6) & 63;
  int b = pix >> 12;
  float a0=0.f, a1=0.f, a2=0.f, a3=0.f;
  #pragma unroll
  for(int kh=0;kh<3;kh++){
    int hh = h + kh - 1;
    if((unsigned)hh < 64u){
      #pragma unroll
      for(int kw=0;kw<3;kw++){
        int ww = w + kw - 1;
        if((unsigned)ww < 64u){
          ushort4 v = *(const ushort4*)(in + (size_t)((b*64+hh)*64 + ww)*CN + c4*4);
          float4 wv = *(const float4*)(wgt + (kh*3+kw)*CN + c4*4);
          a0 += b2f(v.x)*wv.x; a1 += b2f(v.y)*wv.y;
          a2 += b2f(v.z)*wv.z; a3 += b2f(v.w)*wv.w;
        }
      }
    }
  }
  if(ACT==1){ a0=leaky02(a0); a1=leaky02(a1); a2=leaky02(a2); a3=leaky02(a3); }
  else if(ACT==2){ a0=gelu_exact(a0); a1=gelu_exact(a1); a2=gelu_exact(a2); a3=gelu_exact(a3); }
  size_t ob = (size_t)pix*CN + c4*4;
  if(res1){ ushort4 r = *(const ushort4*)(res1 + ob);
            a0+=b2f(r.x); a1+=b2f(r.y); a2+=b2f(r.z); a3+=b2f(r.w); }
  if(res2){ ushort4 r = *(const ushort4*)(res2 + ob);
            a0+=b2f(r.x); a1+=b2f(r.y); a2+=b2f(r.z); a3+=b2f(r.w); }
  ushort4 o; o.x=f2b(a0); o.y=f2b(a1); o.z=f2b(a2); o.w=f2b(a3);
  *(ushort4*)(out + ob) = o;
}

// ---- causal depthwise conv1d (k=4) + silu, 4 d per thread; silu(z) extracted too ----
__global__ void k_causal(const u16* __restrict__ xz, const float* __restrict__ cw,
                         const float* __restrict__ cb, u16* __restrict__ xi,
                         u16* __restrict__ zs){
  int g = blockIdx.x*256 + threadIdx.x;
  int d4 = g & 31;
  int p = g >> 5;            // b*4096 + t
  int t = p & 4095;
  float4 cbv = *(const float4*)(cb + d4*4);
  float a0=cbv.x, a1=cbv.y, a2=cbv.z, a3=cbv.w;
  #pragma unroll
  for(int k=0;k<4;k++){
    if(t + k - 3 >= 0){
      ushort4 v = *(const ushort4*)(xz + (size_t)(p + k - 3)*256 + d4*4);
      float4 wv = *(const float4*)(cw + k*128 + d4*4);
      a0 += b2f(v.x)*wv.x; a1 += b2f(v.y)*wv.y;
      a2 += b2f(v.z)*wv.z; a3 += b2f(v.w)*wv.w;
    }
  }
  ushort4 o; o.x=f2b(silu_(a0)); o.y=f2b(silu_(a1)); o.z=f2b(silu_(a2)); o.w=f2b(silu_(a3));
  *(ushort4*)(xi + (size_t)p*128 + d4*4) = o;
  ushort4 zv = *(const ushort4*)(xz + (size_t)p*256 + 128 + d4*4);
  ushort4 zo; zo.x=f2b(silu_(b2f(zv.x))); zo.y=f2b(silu_(b2f(zv.y)));
  zo.z=f2b(silu_(b2f(zv.z))); zo.w=f2b(silu_(b2f(zv.w)));
  *(ushort4*)(zs + (size_t)p*128 + d4*4) = zo;
}

// ---------------- fuse xproj[:, :4] @ dt_w  ->  Wf[128][128] fp32 ----------------
__global__ void k_fusew(const float* __restrict__ xproj, const float* __restrict__ dtw,
                        float* __restrict__ wf){
  int g = blockIdx.x*256 + threadIdx.x;     // 16384
  int d = g & 127;
  int c = g >> 7;
  float acc = 0.f;
  #pragma unroll
  for(int r=0;r<4;r++) acc += xproj[c*36 + r] * dtw[r*128 + d];
  wf[c*128 + d] = acc;
}

// ------- scan phase 1: thread owns (d, all 16 s) for one (b,chunk); chunk=16 steps -------
// P/Q stored bf16, layout [ch][ (b*128+d)*16 + s ]
__global__ __launch_bounds__(128) void k_scan1(const u16* __restrict__ dt, const u16* __restrict__ xi,
                        const u16* __restrict__ bc, const float* __restrict__ alog,
                        u16* __restrict__ Pb, u16* __restrict__ Qb){
  int blk = blockIdx.x;          // B_*NCH = 2048 blocks of 128
  int ch = blk & (NCH-1);
  int b = blk >> 8;
  int d = threadIdx.x;
  __shared__ __align__(16) u16 sdt[CHL*128], sxi[CHL*128], sbc[CHL*32];
  float A[16], P[16], Q[16];
  #pragma unroll
  for(int s=0;s<16;s++){ A[s] = -__expf(alog[d*16+s]); P[s]=1.f; Q[s]=0.f; }
  int pbase = b*HW_ + ch*CHL;
  const uint4* gdt = (const uint4*)(dt + (size_t)pbase*128);
  const uint4* gxi = (const uint4*)(xi + (size_t)pbase*128);
  ((uint4*)sdt)[d]     = gdt[d];
  ((uint4*)sdt)[d+128] = gdt[d+128];
  ((uint4*)sxi)[d]     = gxi[d];
  ((uint4*)sxi)[d+128] = gxi[d+128];
  if(d < 64) ((uint4*)sbc)[d] = ((const uint4*)(bc + (size_t)pbase*32))[d];
  __syncthreads();
  #pragma unroll
  for(int i=0;i<CHL;i++){
    float dtv = b2f(sdt[i*128+d]);
    float u = dtv * b2f(sxi[i*128+d]);
    #pragma unroll
    for(int s=0;s<16;s++){
      float a = __expf(dtv*A[s]);
      P[s] *= a;
      Q[s] = a*Q[s] + u*b2f(sbc[i*32+s]);
    }
  }
  int gidx = ch*16384 + (b*128+d)*16;
  unsigned pw[8], qw[8];
  #pragma unroll
  for(int j=0;j<8;j++){
    pw[j] = (unsigned)f2b(P[2*j]) | ((unsigned)f2b(P[2*j+1])<<16);
    qw[j] = (unsigned)f2b(Q[2*j]) | ((unsigned)f2b(Q[2*j+1])<<16);
  }
  *(uint4*)(Pb+gidx)   = make_uint4(pw[0],pw[1],pw[2],pw[3]);
  *(uint4*)(Pb+gidx+8) = make_uint4(pw[4],pw[5],pw[6],pw[7]);
  *(uint4*)(Qb+gidx)   = make_uint4(qw[0],qw[1],qw[2],qw[3]);
  *(uint4*)(Qb+gidx+8) = make_uint4(qw[4],qw[5],qw[6],qw[7]);
}

// ---------------- scan phase 2: sequential over 256 chunks ----------------
__global__ void k_scan2(const u16* __restrict__ Pb, const u16* __restrict__ Qb,
                        u16* __restrict__ Hin){
  int g = blockIdx.x*64 + threadIdx.x;     // 16384 = (b,d,s)
  float h = 0.f;
  #pragma unroll 8
  for(int ch=0; ch<NCH; ch++){
    Hin[ch*16384 + g] = f2b(h);
    h = b2f(Pb[ch*16384 + g])*h + b2f(Qb[ch*16384 + g]);
  }
}

// ------- scan phase 3: recompute with real h0, s-reduction in registers, fused epilogue -------
// yss may alias dt (in-place): chunk fully staged to LDS before any write.
__global__ __launch_bounds__(128) void k_scan3(const u16* __restrict__ dt, const u16* __restrict__ xi,
                        const u16* __restrict__ bc, const u16* __restrict__ zs,
                        const float* __restrict__ alog, const float* __restrict__ Dp,
                        const u16* __restrict__ Hin, u16* __restrict__ yss){
  int blk = blockIdx.x;         // 2048 blocks of 128
  int ch = blk & (NCH-1);
  int b = blk >> 8;
  int d = threadIdx.x;
  __shared__ __align__(16) u16 sdt[CHL*128], sxi[CHL*128], szs[CHL*128], sbc[CHL*32];
  float A[16], h[16];
  u16 hbuf[16];
  int gidx = ch*16384 + (b*128+d)*16;
  *(uint4*)hbuf     = *(const uint4*)(Hin+gidx);
  *(uint4*)(hbuf+8) = *(const uint4*)(Hin+gidx+8);
  #pragma unroll
  for(int s=0;s<16;s++){ A[s] = -__expf(alog[d*16+s]); h[s] = b2f(hbuf[s]); }
  float Dd = Dp[d];
  int pbase = b*HW_ + ch*CHL;
  const uint4* gdt = (const uint4*)(dt + (size_t)pbase*128);
  const uint4* gxi = (const uint4*)(xi + (size_t)pbase*128);
  const uint4* gzs = (const uint4*)(zs + (size_t)pbase*128);
  ((uint4*)sdt)[d]     = gdt[d];
  ((uint4*)sdt)[d+128] = gdt[d+128];
  ((uint4*)sxi)[d]     = gxi[d];
  ((uint4*)sxi)[d+128] = gxi[d+128];
  ((uint4*)szs)[d]     = gzs[d];
  ((uint4*)szs)[d+128] = gzs[d+128];
  if(d < 64) ((uint4*)sbc)[d] = ((const uint4*)(bc + (size_t)pbase*32))[d];
  __syncthreads();
  #pragma unroll
  for(int i=0;i<CHL;i++){
    float dtv = b2f(sdt[i*128+d]);
    float xiv = b2f(sxi[i*128+d]);
    float u = dtv*xiv;
    float acc = Dd*xiv;
    #pragma unroll
    for(int s=0;s<16;s++){
      float a = __expf(dtv*A[s]);
      h[s] = a*h[s] + u*b2f(sbc[i*32+s]);
      acc += h[s]*b2f(sbc[i*32+16+s]);
    }
    yss[(size_t)(pbase+i)*128 + d] = f2b(acc * b2f(szs[i*128+d]));
  }
}

extern "C" void kernel_launch(void* const* d_in, const int* in_sizes, int n_in,
                              void* d_out, int out_size, void* d_ws, size_t ws_size,
                              hipStream_t stream) {
  const float* x        = (const float*)d_in[0];
  const float* ln1_g    = (const float*)d_in[1];
  const float* ln1_b    = (const float*)d_in[2];
  const float* vin_w1   = (const float*)d_in[3];
  const float* vin_dw   = (const float*)d_in[4];
  const float* vin_w2   = (const float*)d_in[5];
  const float* vout_dw1 = (const float*)d_in[6];
  const float* vout_dw2 = (const float*)d_in[7];
  const float* ssm_in_w = (const float*)d_in[8];
  const float* ssm_cw   = (const float*)d_in[9];
  const float* ssm_cb   = (const float*)d_in[10];
  const float* ssm_xprj = (const float*)d_in[11];
  const float* ssm_dtw  = (const float*)d_in[12];
  const float* ssm_dtb  = (const float*)d_in[13];
  const float* ssm_Alog = (const float*)d_in[14];
  const float* ssm_D    = (const float*)d_in[15];
  const float* ssm_outw = (const float*)d_in[16];
  const float* ln2_g    = (const float*)d_in[17];
  const float* ln2_b    = (const float*)d_in[18];
  const float* ff_w1    = (const float*)d_in[19];
  const float* ff_dw    = (const float*)d_in[20];
  const float* ff_w2    = (const float*)d_in[21];
  float* out = (float*)d_out;

  // ---- bf16 arena, lifetime-packed (units: bf16 elements), 64MB total ----
  const size_t M = 1u<<20;
  u16* U   = (u16*)d_ws;
  u16* xT  = U;              // [0,2M)    lives to vision-out residual
  u16* tA  = U + 2*M;        // [2M,4M)   } Hin lives here during scan
  u16* tB  = U + 4*M;        // [4M,6M)   }
  u16* x0  = U + 6*M;        // [6M,8M)   x0, later xR
  u16* xi  = U + 8*M;        // [8M,12M)  xi; first 2M later reused as y
  u16* zs  = U + 12*M;       // [12M,16M) silu(z)
  u16* xz  = U + 16*M;       // [16M,24M) xz; dead after causal -> Pb/Qb; later t1; later fin
  u16* dtb = U + 24*M;       // [24M,28M) dt; scan3 writes yss in-place here; later t2 start
  u16* bc  = U + 28*M;       // [28M,29M)
  float* wf  = (float*)(U + 29*M);      // 16K floats in [29M,30M) spare
  u16* Pb  = U + 16*M;       // [16M,20M) 4M u16 (xz dead)
  u16* Qb  = U + 20*M;       // [20M,24M) 4M u16
  u16* Hin = tA;             // [2M,6M)   4M u16 (tA/tB free during SSM)
  u16* yss = dtb;            // in-place over dt
  u16* y   = xi;             // 2M (xi free after scan3)
  u16* t2  = dtb;            // 8M [24M,32M) (dt/bc dead in FFN phase)
  float* fin = (float*)(U + 16*M);   // 2M floats [16M,20M) (dead when ff2 runs)

  // --- vision in path ---
  k_trans_in<<<512,256,0,stream>>>(x, xT);
  k_ln<<<2048,256,0,stream>>>(xT, ln1_g, ln1_b, tA);
  k_mfma<64,64,0,false><<<512,256,0,stream>>>(vin_w1, 64, 0, tA, nullptr, nullptr, tB);
  k_dw3<64,2><<<2048,256,0,stream>>>(tB, vin_dw, nullptr, nullptr, tA);
  k_mfma<64,64,0,false><<<512,256,0,stream>>>(vin_w2, 64, 0, tA, nullptr, nullptr, x0);

  // --- SSM ---
  k_mfma<64,256,0,false><<<512,256,0,stream>>>(ssm_in_w, 256, 0, x0, nullptr, nullptr, xz);
  k_causal<<<4096,256,0,stream>>>(xz, ssm_cw, ssm_cb, xi, zs);
  k_fusew<<<64,256,0,stream>>>(ssm_xprj, ssm_dtw, wf);
  k_mfma<128,128,2,false><<<512,256,0,stream>>>(wf, 128, 0, xi, ssm_dtb, nullptr, dtb);
  k_mfma<128,32,0,false><<<512,256,0,stream>>>(ssm_xprj, 36, 4, xi, nullptr, nullptr, bc);
  k_scan1<<<2048,128,0,stream>>>(dtb, xi, bc, ssm_Alog, Pb, Qb);
  k_scan2<<<256,64,0,stream>>>(Pb, Qb, Hin);
  k_scan3<<<2048,128,0,stream>>>(dtb, xi, bc, zs, ssm_Alog, ssm_D, Hin, yss);
  k_mfma<128,64,0,false><<<512,256,0,stream>>>(ssm_outw, 64, 0, yss, nullptr, x0, y); // y = ssm + x0

  // --- vision out path:  xR = dw2(gelu(dw1(y))) + y + xT ---
  k_dw3<64,2><<<2048,256,0,stream>>>(y, vout_dw1, nullptr, nullptr, tA);
  k_dw3<64,0><<<2048,256,0,stream>>>(tA, vout_dw2, y, xT, x0);   // x0 now = xR

  // --- FFN ---
  k_ln<<<2048,256,0,stream>>>(x0, ln2_g, ln2_b, tB);
  k_mfma<64,256,1,false><<<512,256,0,stream>>>(ff_w1, 256, 0, tB, nullptr, nullptr, xz);  // t1
  k_dw3<256,1><<<8192,256,0,stream>>>(xz, ff_dw, nullptr, nullptr, t2);
  k_mfma<256,64,0,true><<<512,256,0,stream>>>(ff_w2, 64, 0, t2, nullptr, x0, fin);        // + xR

  k_trans_out<<<512,256,0,stream>>>(fin, out);
}

// Round 7
// 325.000 us; speedup vs baseline: 3.3956x; 1.0732x over previous
//
#include <hip/hip_runtime.h>
#include <hip/hip_bf16.h>
#include <math.h>

typedef unsigned short u16;   // bf16 storage
typedef __attribute__((ext_vector_type(8))) short s8v;    // 8 bf16 = 4 VGPR
typedef __attribute__((ext_vector_type(4))) float f4v;    // MFMA acc

#define B_    8
#define C_    64
#define HW_   4096
#define NPIX  32768     // B_*HW_
#define DI    128
#define NCH   256
#define CHL   16        // HW_/NCH

__device__ __forceinline__ float b2f(u16 v){ return __uint_as_float(((unsigned)v)<<16); }
__device__ __forceinline__ u16 f2b(float x){
  unsigned u = __float_as_uint(x);
  u += 0x7fff + ((u >> 16) & 1);      // RTNE
  return (u16)(u >> 16);
}
__device__ __forceinline__ float gelu_exact(float x){ return 0.5f*x*(1.0f+erff(x*0.70710678118654752f)); }
__device__ __forceinline__ float leaky02(float x){ return x>0.f ? x : 0.2f*x; }
__device__ __forceinline__ float softplus_(float x){ return fmaxf(x,0.f)+log1pf(__expf(-fabsf(x))); }
__device__ __forceinline__ float silu_(float x){ return x / (1.0f + __expf(-x)); }

// ------- NCHW fp32 -> NHWC bf16 (xT) + fused LayerNorm -> NHWC bf16 (lnout) -------
__global__ void k_trans_ln(const float* __restrict__ x, u16* __restrict__ xT,
                           u16* __restrict__ lnout, const float* __restrict__ g,
                           const float* __restrict__ bta){
  __shared__ float tile[64][65];
  int blk = blockIdx.x;            // B_ * (HW_/64) = 512
  int b = blk >> 6;
  int hwb = (blk & 63) << 6;
  int lane = threadIdx.x & 63, row = threadIdx.x >> 6;
  const float* src = x + (size_t)b*C_*HW_;
  #pragma unroll
  for(int k=0;k<16;k++){
    int c = row + 4*k;
    tile[c][lane] = src[c*HW_ + hwb + lane];
  }
  __syncthreads();
  u16* dst = xT + (size_t)b*HW_*C_;
  #pragma unroll
  for(int k=0;k<16;k++){
    int hwl = row + 4*k;
    dst[(hwb+hwl)*C_ + lane] = f2b(tile[lane][hwl]);
  }
  // LN: wave handles 16 pixels; lane = channel
  float gg = g[lane], bb = bta[lane];
  u16* ldst = lnout + (size_t)b*HW_*C_;
  #pragma unroll
  for(int i=0;i<16;i++){
    int hwl = row*16 + i;
    float v = tile[lane][hwl];
    float s = v, sq = v*v;
    #pragma unroll
    for(int o=32;o>0;o>>=1){ s += __shfl_xor(s,o); sq += __shfl_xor(sq,o); }
    float m = s*(1.f/64.f);
    float var = sq*(1.f/64.f) - m*m;
    float r = rsqrtf(var + 1e-5f);
    ldst[(hwb+hwl)*C_ + lane] = f2b((v-m)*r*gg + bb);
  }
}

// ========== generic MFMA matmul: [NPIX,CIN](bf16) @ [CIN,COUT](fp32->bf16) ==========
template<int CIN, int COUT, int ACT, bool OUTF32>
__global__ __launch_bounds__(256) void k_mfma(const float* __restrict__ W, int ldw, int wofs,
                     const u16* __restrict__ in, const float* __restrict__ bias,
                     const u16* __restrict__ res, void* __restrict__ outv){
  const int KCH = (CIN < 128) ? CIN : 128;
  const int LDA = KCH + 8;
  const int NS  = COUT / 16;
  __shared__ __align__(16) u16 sA[64*LDA];
  __shared__ __align__(16) u16 sW[COUT*LDA];
  int tid = threadIdx.x;
  int p0 = blockIdx.x * 64;
  int ln = tid & 63, wv = tid >> 6;
  int mrow = ln & 15, quad = ln >> 4;
  f4v acc[NS];
  #pragma unroll
  for(int i=0;i<NS;i++) acc[i] = (f4v){0.f,0.f,0.f,0.f};
  const u16* aBase = sA + (wv*16 + mrow)*LDA + quad*8;
  const u16* wBase = sW + mrow*LDA + quad*8;
  for(int k0=0; k0<CIN; k0+=KCH){
    if(k0) __syncthreads();
    for(int idx=tid*4; idx<KCH*COUT; idx+=1024){
      int c = idx / COUT, n = idx % COUT;
      float4 w = *(const float4*)(&W[(size_t)(k0+c)*ldw + wofs + n]);
      u16* dst = sW + n*LDA + c;
      dst[0]=f2b(w.x); dst[LDA]=f2b(w.y); dst[2*LDA]=f2b(w.z); dst[3*LDA]=f2b(w.w);
    }
    const int RW = KCH/8;
    for(int g=tid; g<64*RW; g+=256){
      int row = g / RW, c8 = (g % RW)*8;
      *(uint4*)(sA + row*LDA + c8) = *(const uint4*)(in + (size_t)(p0+row)*CIN + k0 + c8);
    }
    __syncthreads();
    #pragma unroll
    for(int kk=0; kk<KCH; kk+=32){
      s8v af = *(const s8v*)(aBase + kk);
      #pragma unroll
      for(int ns=0; ns<NS; ns++){
        s8v bf = *(const s8v*)(wBase + ns*16*LDA + kk);
        acc[ns] = __builtin_amdgcn_mfma_f32_16x16x32_bf16(af, bf, acc[ns], 0, 0, 0);
      }
    }
  }
  int pr = p0 + wv*16 + quad*4;
  #pragma unroll
  for(int ns=0; ns<NS; ns++){
    int n = ns*16 + mrow;
    float bs = bias ? bias[n] : 0.f;
    #pragma unroll
    for(int r=0;r<4;r++){
      float v = acc[ns][r] + bs;
      if(ACT==1) v = leaky02(v);
      else if(ACT==2) v = softplus_(v);
      if(res) v += b2f(res[(size_t)(pr+r)*COUT + n]);
      if(OUTF32) ((float*)outv)[(size_t)(pr+r)*COUT + n] = v;
      else       ((u16*)outv)[(size_t)(pr+r)*COUT + n] = f2b(v);
    }
  }
}

// ========== MFMA with fused LayerNorm on A (CIN=64) ==========
template<int COUT, int ACT>
__global__ __launch_bounds__(256) void k_mfma_ln(const float* __restrict__ W, int ldw,
                     const u16* __restrict__ in, const float* __restrict__ g,
                     const float* __restrict__ bta, u16* __restrict__ outp){
  const int CIN = 64, LDA = 72, NS = COUT/16;
  __shared__ __align__(16) u16 sA[64*LDA];
  __shared__ __align__(16) u16 sW[COUT*LDA];
  int tid = threadIdx.x;
  int p0 = blockIdx.x * 64;
  int ln = tid & 63, wv = tid >> 6;
  int mrow = ln & 15, quad = ln >> 4;
  for(int idx=tid*4; idx<CIN*COUT; idx+=1024){
    int c = idx / COUT, n = idx % COUT;
    float4 w = *(const float4*)(&W[(size_t)c*ldw + n]);
    u16* dst = sW + n*LDA + c;
    dst[0]=f2b(w.x); dst[LDA]=f2b(w.y); dst[2*LDA]=f2b(w.z); dst[3*LDA]=f2b(w.w);
  }
  // LN staging: wave wv handles rows wv*16..+15, lane = channel
  float gg = g[ln], bb = bta[ln];
  #pragma unroll
  for(int i=0;i<16;i++){
    int row = wv*16 + i;
    float v = b2f(in[(size_t)(p0+row)*64 + ln]);
    float s = v, sq = v*v;
    #pragma unroll
    for(int o=32;o>0;o>>=1){ s += __shfl_xor(s,o); sq += __shfl_xor(sq,o); }
    float m = s*(1.f/64.f);
    float var = sq*(1.f/64.f) - m*m;
    float r = rsqrtf(var + 1e-5f);
    sA[row*LDA + ln] = f2b((v-m)*r*gg + bb);
  }
  __syncthreads();
  f4v acc[NS];
  #pragma unroll
  for(int i=0;i<NS;i++) acc[i] = (f4v){0.f,0.f,0.f,0.f};
  const u16* aBase = sA + (wv*16 + mrow)*LDA + quad*8;
  const u16* wBase = sW + mrow*LDA + quad*8;
  #pragma unroll
  for(int kk=0; kk<CIN; kk+=32){
    s8v af = *(const s8v*)(aBase + kk);
    #pragma unroll
    for(int ns=0; ns<NS; ns++){
      s8v bf = *(const s8v*)(wBase + ns*16*LDA + kk);
      acc[ns] = __builtin_amdgcn_mfma_f32_16x16x32_bf16(af, bf, acc[ns], 0, 0, 0);
    }
  }
  int pr = p0 + wv*16 + quad*4;
  #pragma unroll
  for(int ns=0; ns<NS; ns++){
    int n = ns*16 + mrow;
    #pragma unroll
    for(int r=0;r<4;r++){
      float v = acc[ns][r];
      if(ACT==1) v = leaky02(v);
      outp[(size_t)(pr+r)*COUT + n] = f2b(v);
    }
  }
}

// ========== combined dt/bc MFMA: [NPIX,128] @ [128,160], split epilogue ==========
__global__ __launch_bounds__(256) void k_mfma_dtbc(const float* __restrict__ W2,
                     const u16* __restrict__ in, const float* __restrict__ dtbias,
                     u16* __restrict__ dtout, u16* __restrict__ bcout){
  const int CIN=128, COUT=160, LDA=136, NS=10;
  __shared__ __align__(16) u16 sA[64*LDA];
  __shared__ __align__(16) u16 sW[COUT*LDA];
  int tid = threadIdx.x;
  int p0 = blockIdx.x * 64;
  int ln = tid & 63, wv = tid >> 6;
  int mrow = ln & 15, quad = ln >> 4;
  for(int idx=tid*4; idx<CIN*COUT; idx+=1024){
    int c = idx / COUT, n = idx % COUT;
    float4 w = *(const float4*)(&W2[(size_t)c*COUT + n]);
    u16* dst = sW + n*LDA + c;
    dst[0]=f2b(w.x); dst[LDA]=f2b(w.y); dst[2*LDA]=f2b(w.z); dst[3*LDA]=f2b(w.w);
  }
  for(int g=tid; g<64*16; g+=256){
    int row = g >> 4, c8 = (g & 15)*8;
    *(uint4*)(sA + row*LDA + c8) = *(const uint4*)(in + (size_t)(p0+row)*CIN + c8);
  }
  __syncthreads();
  f4v acc[NS];
  #pragma unroll
  for(int i=0;i<NS;i++) acc[i] = (f4v){0.f,0.f,0.f,0.f};
  const u16* aBase = sA + (wv*16 + mrow)*LDA + quad*8;
  const u16* wBase = sW + mrow*LDA + quad*8;
  #pragma unroll
  for(int kk=0; kk<CIN; kk+=32){
    s8v af = *(const s8v*)(aBase + kk);
    #pragma unroll
    for(int ns=0; ns<NS; ns++){
      s8v bf = *(const s8v*)(wBase + ns*16*LDA + kk);
      acc[ns] = __builtin_amdgcn_mfma_f32_16x16x32_bf16(af, bf, acc[ns], 0, 0, 0);
    }
  }
  int pr = p0 + wv*16 + quad*4;
  #pragma unroll
  for(int ns=0; ns<NS; ns++){
    int n = ns*16 + mrow;
    if(n < 128){
      float bs = dtbias[n];
      #pragma unroll
      for(int r=0;r<4;r++)
        dtout[(size_t)(pr+r)*128 + n] = f2b(softplus_(acc[ns][r] + bs));
    }else{
      #pragma unroll
      for(int r=0;r<4;r++)
        bcout[(size_t)(pr+r)*32 + (n-128)] = f2b(acc[ns][r]);
    }
  }
}

// ========== final MFMA: [NPIX,256] @ [256,64] + res, fp32 NCHW store ==========
__global__ __launch_bounds__(256) void k_mfma_fin(const float* __restrict__ W,
                     const u16* __restrict__ in, const u16* __restrict__ res,
                     float* __restrict__ outp){
  const int CIN=256, COUT=64, KCH=128, LDA=136, NS=4;
  __shared__ __align__(16) u16 sA[64*LDA];
  __shared__ __align__(16) u16 sW[COUT*LDA];
  int tid = threadIdx.x;
  int p0 = blockIdx.x * 64;
  int ln = tid & 63, wv = tid >> 6;
  int mrow = ln & 15, quad = ln >> 4;
  f4v acc[NS];
  #pragma unroll
  for(int i=0;i<NS;i++) acc[i] = (f4v){0.f,0.f,0.f,0.f};
  const u16* aBase = sA + (wv*16 + mrow)*LDA + quad*8;
  const u16* wBase = sW + mrow*LDA + quad*8;
  for(int k0=0; k0<CIN; k0+=KCH){
    if(k0) __syncthreads();
    for(int idx=tid*4; idx<KCH*COUT; idx+=1024){
      int c = idx / COUT, n = idx % COUT;
      float4 w = *(const float4*)(&W[(size_t)(k0+c)*COUT + n]);
      u16* dst = sW + n*LDA + c;
      dst[0]=f2b(w.x); dst[LDA]=f2b(w.y); dst[2*LDA]=f2b(w.z); dst[3*LDA]=f2b(w.w);
    }
    for(int g=tid; g<64*16; g+=256){
      int row = g >> 4, c8 = (g & 15)*8;
      *(uint4*)(sA + row*LDA + c8) = *(const uint4*)(in + (size_t)(p0+row)*CIN + k0 + c8);
    }
    __syncthreads();
    #pragma unroll
    for(int kk=0; kk<KCH; kk+=32){
      s8v af = *(const s8v*)(aBase + kk);
      #pragma unroll
      for(int ns=0; ns<NS; ns++){
        s8v bf = *(const s8v*)(wBase + ns*16*LDA + kk);
        acc[ns] = __builtin_amdgcn_mfma_f32_16x16x32_bf16(af, bf, acc[ns], 0, 0, 0);
      }
    }
  }
  int pr = p0 + wv*16 + quad*4;
  int b = blockIdx.x >> 6;
  int hwr = ((blockIdx.x & 63) << 6) + wv*16 + quad*4;
  #pragma unroll
  for(int ns=0; ns<NS; ns++){
    int n = ns*16 + mrow;
    float4 v4;
    v4.x = acc[ns][0] + b2f(res[(size_t)(pr+0)*64 + n]);
    v4.y = acc[ns][1] + b2f(res[(size_t)(pr+1)*64 + n]);
    v4.z = acc[ns][2] + b2f(res[(size_t)(pr+2)*64 + n]);
    v4.w = acc[ns][3] + b2f(res[(size_t)(pr+3)*64 + n]);
    *(float4*)(outp + (size_t)b*C_*HW_ + (size_t)n*HW_ + hwr) = v4;
  }
}

// ---------------- depthwise 3x3 SAME, 4 channels per thread ----------------
template<int CN, int ACT>   // ACT: 0 none, 1 leaky, 2 gelu
__global__ void k_dw3(const u16* __restrict__ in, const float* __restrict__ wgt,
                      const u16* __restrict__ res1, const u16* __restrict__ res2,
                      u16* __restrict__ out){
  const int C4 = CN/4;
  int g = blockIdx.x*256 + threadIdx.x;
  int c4 = g % C4;
  int pix = g / C4;
  int w = pix & 63;
  int h = (pix >> 6) & 63;
  int b = pix >> 12;
  float a0=0.f, a1=0.f, a2=0.f, a3=0.f;
  #pragma unroll
  for(int kh=0;kh<3;kh++){
    int hh = h + kh - 1;
    if((unsigned)hh < 64u){
      #pragma unroll
      for(int kw=0;kw<3;kw++){
        int ww = w + kw - 1;
        if((unsigned)ww < 64u){
          ushort4 v = *(const ushort4*)(in + (size_t)((b*64+hh)*64 + ww)*CN + c4*4);
          float4 wv = *(const float4*)(wgt + (kh*3+kw)*CN + c4*4);
          a0 += b2f(v.x)*wv.x; a1 += b2f(v.y)*wv.y;
          a2 += b2f(v.z)*wv.z; a3 += b2f(v.w)*wv.w;
        }
      }
    }
  }
  if(ACT==1){ a0=leaky02(a0); a1=leaky02(a1); a2=leaky02(a2); a3=leaky02(a3); }
  else if(ACT==2){ a0=gelu_exact(a0); a1=gelu_exact(a1); a2=gelu_exact(a2); a3=gelu_exact(a3); }
  size_t ob = (size_t)pix*CN + c4*4;
  if(res1){ ushort4 r = *(const ushort4*)(res1 + ob);
            a0+=b2f(r.x); a1+=b2f(r.y); a2+=b2f(r.z); a3+=b2f(r.w); }
  if(res2){ ushort4 r = *(const ushort4*)(res2 + ob);
            a0+=b2f(r.x); a1+=b2f(r.y); a2+=b2f(r.z); a3+=b2f(r.w); }
  ushort4 o; o.x=f2b(a0); o.y=f2b(a1); o.z=f2b(a2); o.w=f2b(a3);
  *(ushort4*)(out + ob) = o;
}

// ---- causal depthwise conv1d (k=4) + silu, 4 d per thread; silu(z) extracted too ----
__global__ void k_causal(const u16* __restrict__ xz, const float* __restrict__ cw,
                         const float* __restrict__ cb, u16* __restrict__ xi,
                         u16* __restrict__ zs){
  int g = blockIdx.x*256 + threadIdx.x;
  int d4 = g & 31;
  int p = g >> 5;            // b*4096 + t
  int t = p & 4095;
  float4 cbv = *(const float4*)(cb + d4*4);
  float a0=cbv.x, a1=cbv.y, a2=cbv.z, a3=cbv.w;
  #pragma unroll
  for(int k=0;k<4;k++){
    if(t + k - 3 >= 0){
      ushort4 v = *(const ushort4*)(xz + (size_t)(p + k - 3)*256 + d4*4);
      float4 wv = *(const float4*)(cw + k*128 + d4*4);
      a0 += b2f(v.x)*wv.x; a1 += b2f(v.y)*wv.y;
      a2 += b2f(v.z)*wv.z; a3 += b2f(v.w)*wv.w;
    }
  }
  ushort4 o; o.x=f2b(silu_(a0)); o.y=f2b(silu_(a1)); o.z=f2b(silu_(a2)); o.w=f2b(silu_(a3));
  *(ushort4*)(xi + (size_t)p*128 + d4*4) = o;
  ushort4 zv = *(const ushort4*)(xz + (size_t)p*256 + 128 + d4*4);
  ushort4 zo; zo.x=f2b(silu_(b2f(zv.x))); zo.y=f2b(silu_(b2f(zv.y)));
  zo.z=f2b(silu_(b2f(zv.z))); zo.w=f2b(silu_(b2f(zv.w)));
  *(ushort4*)(zs + (size_t)p*128 + d4*4) = zo;
}

// ------- build combined W2 [128][160]: cols 0..127 = xproj[:,:4]@dtw, 128..159 = xproj[:,4:36] -------
__global__ void k_fusew2(const float* __restrict__ xproj, const float* __restrict__ dtw,
                         float* __restrict__ w2){
  int g = blockIdx.x*256 + threadIdx.x;     // 128*160 = 20480
  if(g >= 20480) return;
  int n = g % 160;
  int c = g / 160;
  float v;
  if(n < 128){
    v = 0.f;
    #pragma unroll
    for(int r=0;r<4;r++) v += xproj[c*36 + r] * dtw[r*128 + n];
  }else{
    v = xproj[c*36 + 4 + (n-128)];
  }
  w2[c*160 + n] = v;
}

// ------- scan phase 1 -------
__global__ __launch_bounds__(128) void k_scan1(const u16* __restrict__ dt, const u16* __restrict__ xi,
                        const u16* __restrict__ bc, const float* __restrict__ alog,
                        u16* __restrict__ Pb, u16* __restrict__ Qb){
  int blk = blockIdx.x;          // B_*NCH = 2048 blocks of 128
  int ch = blk & (NCH-1);
  int b = blk >> 8;
  int d = threadIdx.x;
  __shared__ __align__(16) u16 sdt[CHL*128], sxi[CHL*128], sbc[CHL*32];
  float A[16], P[16], Q[16];
  #pragma unroll
  for(int s=0;s<16;s++){ A[s] = -__expf(alog[d*16+s]); P[s]=1.f; Q[s]=0.f; }
  int pbase = b*HW_ + ch*CHL;
  const uint4* gdt = (const uint4*)(dt + (size_t)pbase*128);
  const uint4* gxi = (const uint4*)(xi + (size_t)pbase*128);
  ((uint4*)sdt)[d]     = gdt[d];
  ((uint4*)sdt)[d+128] = gdt[d+128];
  ((uint4*)sxi)[d]     = gxi[d];
  ((uint4*)sxi)[d+128] = gxi[d+128];
  if(d < 64) ((uint4*)sbc)[d] = ((const uint4*)(bc + (size_t)pbase*32))[d];
  __syncthreads();
  #pragma unroll
  for(int i=0;i<CHL;i++){
    float dtv = b2f(sdt[i*128+d]);
    float u = dtv * b2f(sxi[i*128+d]);
    #pragma unroll
    for(int s=0;s<16;s++){
      float a = __expf(dtv*A[s]);
      P[s] *= a;
      Q[s] = a*Q[s] + u*b2f(sbc[i*32+s]);
    }
  }
  int gidx = ch*16384 + (b*128+d)*16;
  unsigned pw[8], qw[8];
  #pragma unroll
  for(int j=0;j<8;j++){
    pw[j] = (unsigned)f2b(P[2*j]) | ((unsigned)f2b(P[2*j+1])<<16);
    qw[j] = (unsigned)f2b(Q[2*j]) | ((unsigned)f2b(Q[2*j+1])<<16);
  }
  *(uint4*)(Pb+gidx)   = make_uint4(pw[0],pw[1],pw[2],pw[3]);
  *(uint4*)(Pb+gidx+8) = make_uint4(pw[4],pw[5],pw[6],pw[7]);
  *(uint4*)(Qb+gidx)   = make_uint4(qw[0],qw[1],qw[2],qw[3]);
  *(uint4*)(Qb+gidx+8) = make_uint4(qw[4],qw[5],qw[6],qw[7]);
}

// ---------------- scan phase 2 ----------------
__global__ void k_scan2(const u16* __restrict__ Pb, const u16* __restrict__ Qb,
                        u16* __restrict__ Hin){
  int g = blockIdx.x*64 + threadIdx.x;     // 16384 = (b,d,s)
  float h = 0.f;
  #pragma unroll 8
  for(int ch=0; ch<NCH; ch++){
    Hin[ch*16384 + g] = f2b(h);
    h = b2f(Pb[ch*16384 + g])*h + b2f(Qb[ch*16384 + g]);
  }
}

// ------- scan phase 3 (yss in-place over dt) -------
__global__ __launch_bounds__(128) void k_scan3(const u16* __restrict__ dt, const u16* __restrict__ xi,
                        const u16* __restrict__ bc, const u16* __restrict__ zs,
                        const float* __restrict__ alog, const float* __restrict__ Dp,
                        const u16* __restrict__ Hin, u16* __restrict__ yss){
  int blk = blockIdx.x;         // 2048 blocks of 128
  int ch = blk & (NCH-1);
  int b = blk >> 8;
  int d = threadIdx.x;
  __shared__ __align__(16) u16 sdt[CHL*128], sxi[CHL*128], szs[CHL*128], sbc[CHL*32];
  float A[16], h[16];
  u16 hbuf[16];
  int gidx = ch*16384 + (b*128+d)*16;
  *(uint4*)hbuf     = *(const uint4*)(Hin+gidx);
  *(uint4*)(hbuf+8) = *(const uint4*)(Hin+gidx+8);
  #pragma unroll
  for(int s=0;s<16;s++){ A[s] = -__expf(alog[d*16+s]); h[s] = b2f(hbuf[s]); }
  float Dd = Dp[d];
  int pbase = b*HW_ + ch*CHL;
  const uint4* gdt = (const uint4*)(dt + (size_t)pbase*128);
  const uint4* gxi = (const uint4*)(xi + (size_t)pbase*128);
  const uint4* gzs = (const uint4*)(zs + (size_t)pbase*128);
  ((uint4*)sdt)[d]     = gdt[d];
  ((uint4*)sdt)[d+128] = gdt[d+128];
  ((uint4*)sxi)[d]     = gxi[d];
  ((uint4*)sxi)[d+128] = gxi[d+128];
  ((uint4*)szs)[d]     = gzs[d];
  ((uint4*)szs)[d+128] = gzs[d+128];
  if(d < 64) ((uint4*)sbc)[d] = ((const uint4*)(bc + (size_t)pbase*32))[d];
  __syncthreads();
  #pragma unroll
  for(int i=0;i<CHL;i++){
    float dtv = b2f(sdt[i*128+d]);
    float xiv = b2f(sxi[i*128+d]);
    float u = dtv*xiv;
    float acc = Dd*xiv;
    #pragma unroll
    for(int s=0;s<16;s++){
      float a = __expf(dtv*A[s]);
      h[s] = a*h[s] + u*b2f(sbc[i*32+s]);
      acc += h[s]*b2f(sbc[i*32+16+s]);
    }
    yss[(size_t)(pbase+i)*128 + d] = f2b(acc * b2f(szs[i*128+d]));
  }
}

extern "C" void kernel_launch(void* const* d_in, const int* in_sizes, int n_in,
                              void* d_out, int out_size, void* d_ws, size_t ws_size,
                              hipStream_t stream) {
  const float* x        = (const float*)d_in[0];
  const float* ln1_g    = (const float*)d_in[1];
  const float* ln1_b    = (const float*)d_in[2];
  const float* vin_w1   = (const float*)d_in[3];
  const float* vin_dw   = (const float*)d_in[4];
  const float* vin_w2   = (const float*)d_in[5];
  const float* vout_dw1 = (const float*)d_in[6];
  const float* vout_dw2 = (const float*)d_in[7];
  const float* ssm_in_w = (const float*)d_in[8];
  const float* ssm_cw   = (const float*)d_in[9];
  const float* ssm_cb   = (const float*)d_in[10];
  const float* ssm_xprj = (const float*)d_in[11];
  const float* ssm_dtw  = (const float*)d_in[12];
  const float* ssm_dtb  = (const float*)d_in[13];
  const float* ssm_Alog = (const float*)d_in[14];
  const float* ssm_D    = (const float*)d_in[15];
  const float* ssm_outw = (const float*)d_in[16];
  const float* ln2_g    = (const float*)d_in[17];
  const float* ln2_b    = (const float*)d_in[18];
  const float* ff_w1    = (const float*)d_in[19];
  const float* ff_dw    = (const float*)d_in[20];
  const float* ff_w2    = (const float*)d_in[21];
  float* out = (float*)d_out;

  // ---- bf16 arena, lifetime-packed (units: bf16 elements) ----
  const size_t M = 1u<<20;
  u16* U   = (u16*)d_ws;
  u16* xT  = U;              // [0,2M)    lives to vision-out residual
  u16* tA  = U + 2*M;        // [2M,4M)   } Hin here during scan
  u16* tB  = U + 4*M;        // [4M,6M)   }
  u16* x0  = U + 6*M;        // [6M,8M)   x0, later xR
  u16* xi  = U + 8*M;        // [8M,12M)  xi; first 2M later reused as y
  u16* zs  = U + 12*M;       // [12M,16M) silu(z)
  u16* xz  = U + 16*M;       // [16M,24M) xz; dead after causal -> Pb/Qb; later t1
  u16* dtb = U + 24*M;       // [24M,28M) dt; scan3 writes yss in-place; later t2 start
  u16* bc  = U + 28*M;       // [28M,29M)
  float* wf2 = (float*)(U + 29*M);   // 20480 floats in [29M,30M) spare
  u16* Pb  = U + 16*M;       // [16M,20M) (xz dead)
  u16* Qb  = U + 20*M;       // [20M,24M)
  u16* Hin = tA;             // [2M,6M)   (tA/tB free during SSM)
  u16* yss = dtb;            // in-place over dt
  u16* y   = xi;             // (xi free after scan3)
  u16* t2  = dtb;            // [24M,32M) (dt/bc dead in FFN phase)

  // --- vision in path ---
  k_trans_ln<<<512,256,0,stream>>>(x, xT, tA, ln1_g, ln1_b);
  k_mfma<64,64,0,false><<<512,256,0,stream>>>(vin_w1, 64, 0, tA, nullptr, nullptr, tB);
  k_dw3<64,2><<<2048,256,0,stream>>>(tB, vin_dw, nullptr, nullptr, tA);
  k_mfma<64,64,0,false><<<512,256,0,stream>>>(vin_w2, 64, 0, tA, nullptr, nullptr, x0);

  // --- SSM ---
  k_mfma<64,256,0,false><<<512,256,0,stream>>>(ssm_in_w, 256, 0, x0, nullptr, nullptr, xz);
  k_causal<<<4096,256,0,stream>>>(xz, ssm_cw, ssm_cb, xi, zs);
  k_fusew2<<<80,256,0,stream>>>(ssm_xprj, ssm_dtw, wf2);
  k_mfma_dtbc<<<512,256,0,stream>>>(wf2, xi, ssm_dtb, dtb, bc);
  k_scan1<<<2048,128,0,stream>>>(dtb, xi, bc, ssm_Alog, Pb, Qb);
  k_scan2<<<256,64,0,stream>>>(Pb, Qb, Hin);
  k_scan3<<<2048,128,0,stream>>>(dtb, xi, bc, zs, ssm_Alog, ssm_D, Hin, yss);
  k_mfma<128,64,0,false><<<512,256,0,stream>>>(ssm_outw, 64, 0, yss, nullptr, x0, y); // y = ssm + x0

  // --- vision out path:  xR = dw2(gelu(dw1(y))) + y + xT ---
  k_dw3<64,2><<<2048,256,0,stream>>>(y, vout_dw1, nullptr, nullptr, tA);
  k_dw3<64,0><<<2048,256,0,stream>>>(tA, vout_dw2, y, xT, x0);   // x0 now = xR

  // --- FFN (LN fused into ff_w1; trans_out fused into ff_w2) ---
  k_mfma_ln<256,1><<<512,256,0,stream>>>(ff_w1, 256, x0, ln2_g, ln2_b, xz);  // t1
  k_dw3<256,1><<<8192,256,0,stream>>>(xz, ff_dw, nullptr, nullptr, t2);
  k_mfma_fin<<<512,256,0,stream>>>(ff_w2, t2, x0, out);
}

// Round 8
// 312.928 us; speedup vs baseline: 3.5266x; 1.0386x over previous
//
#include <hip/hip_runtime.h>
#include <hip/hip_bf16.h>
#include <math.h>

typedef unsigned short u16;   // bf16 storage
typedef __attribute__((ext_vector_type(8))) short s8v;    // 8 bf16 = 4 VGPR
typedef __attribute__((ext_vector_type(4))) float f4v;    // MFMA acc

#define B_    8
#define C_    64
#define HW_   4096
#define NPIX  32768     // B_*HW_
#define DI    128
#define NCH   256
#define CHL   16        // HW_/NCH

__device__ __forceinline__ float b2f(u16 v){ return __uint_as_float(((unsigned)v)<<16); }
__device__ __forceinline__ u16 f2b(float x){
  unsigned u = __float_as_uint(x);
  u += 0x7fff + ((u >> 16) & 1);      // RTNE
  return (u16)(u >> 16);
}
__device__ __forceinline__ float gelu_exact(float x){ return 0.5f*x*(1.0f+erff(x*0.70710678118654752f)); }
__device__ __forceinline__ float leaky02(float x){ return x>0.f ? x : 0.2f*x; }
__device__ __forceinline__ float softplus_(float x){ return fmaxf(x,0.f)+log1pf(__expf(-fabsf(x))); }
__device__ __forceinline__ float silu_(float x){ return x / (1.0f + __expf(-x)); }

// ====== fused: NCHW fp32 -> (xT bf16 NHWC) + LayerNorm + vin_w1 MFMA -> outp ======
__global__ __launch_bounds__(256) void k_trans_ln_mm(const float* __restrict__ x,
                     const float* __restrict__ g, const float* __restrict__ bta,
                     const float* __restrict__ W,
                     u16* __restrict__ xT, u16* __restrict__ outp){
  const int LDA = 72, NS = 4;
  __shared__ float tile[64][65];
  __shared__ __align__(16) u16 sA[64*LDA];
  __shared__ __align__(16) u16 sW[64*LDA];
  int tid = threadIdx.x;
  int blk = blockIdx.x;            // 512
  int b = blk >> 6;
  int hwb = (blk & 63) << 6;
  int lane = tid & 63, row = tid >> 6;
  const float* src = x + (size_t)b*C_*HW_;
  #pragma unroll
  for(int k=0;k<16;k++){
    int c = row + 4*k;
    tile[c][lane] = src[c*HW_ + hwb + lane];
  }
  for(int idx=tid*4; idx<64*64; idx+=1024){
    int c = idx >> 6, n = idx & 63;
    float4 w = *(const float4*)(&W[(size_t)c*64 + n]);
    u16* dst = sW + n*LDA + c;
    dst[0]=f2b(w.x); dst[LDA]=f2b(w.y); dst[2*LDA]=f2b(w.z); dst[3*LDA]=f2b(w.w);
  }
  __syncthreads();
  u16* dstT = xT + (size_t)b*HW_*C_;
  #pragma unroll
  for(int k=0;k<16;k++){
    int hwl = row + 4*k;
    dstT[(hwb+hwl)*C_ + lane] = f2b(tile[lane][hwl]);
  }
  float gg = g[lane], bb = bta[lane];
  #pragma unroll
  for(int i=0;i<16;i++){
    int hwl = row*16 + i;
    float v = tile[lane][hwl];
    float s = v, sq = v*v;
    #pragma unroll
    for(int o=32;o>0;o>>=1){ s += __shfl_xor(s,o); sq += __shfl_xor(sq,o); }
    float m = s*(1.f/64.f);
    float var = sq*(1.f/64.f) - m*m;
    float r = rsqrtf(var + 1e-5f);
    sA[hwl*LDA + lane] = f2b((v-m)*r*gg + bb);
  }
  __syncthreads();
  int ln = tid & 63, wv = tid >> 6;
  int mrow = ln & 15, quad = ln >> 4;
  f4v acc[NS];
  #pragma unroll
  for(int i=0;i<NS;i++) acc[i] = (f4v){0.f,0.f,0.f,0.f};
  const u16* aBase = sA + (wv*16 + mrow)*LDA + quad*8;
  const u16* wBase = sW + mrow*LDA + quad*8;
  #pragma unroll
  for(int kk=0; kk<64; kk+=32){
    s8v af = *(const s8v*)(aBase + kk);
    #pragma unroll
    for(int ns=0; ns<NS; ns++){
      s8v bf = *(const s8v*)(wBase + ns*16*LDA + kk);
      acc[ns] = __builtin_amdgcn_mfma_f32_16x16x32_bf16(af, bf, acc[ns], 0, 0, 0);
    }
  }
  int p0 = blk*64;
  int pr = p0 + wv*16 + quad*4;
  #pragma unroll
  for(int ns=0; ns<NS; ns++){
    int n = ns*16 + mrow;
    #pragma unroll
    for(int r=0;r<4;r++)
      outp[(size_t)(pr+r)*64 + n] = f2b(acc[ns][r]);
  }
}

// ========== generic MFMA matmul: [NPIX,CIN](bf16) @ [CIN,COUT](fp32->bf16) ==========
template<int CIN, int COUT, int ACT, bool OUTF32>
__global__ __launch_bounds__(256) void k_mfma(const float* __restrict__ W, int ldw, int wofs,
                     const u16* __restrict__ in, const float* __restrict__ bias,
                     const u16* __restrict__ res, void* __restrict__ outv){
  const int KCH = (CIN < 128) ? CIN : 128;
  const int LDA = KCH + 8;
  const int NS  = COUT / 16;
  __shared__ __align__(16) u16 sA[64*LDA];
  __shared__ __align__(16) u16 sW[COUT*LDA];
  int tid = threadIdx.x;
  int p0 = blockIdx.x * 64;
  int ln = tid & 63, wv = tid >> 6;
  int mrow = ln & 15, quad = ln >> 4;
  f4v acc[NS];
  #pragma unroll
  for(int i=0;i<NS;i++) acc[i] = (f4v){0.f,0.f,0.f,0.f};
  const u16* aBase = sA + (wv*16 + mrow)*LDA + quad*8;
  const u16* wBase = sW + mrow*LDA + quad*8;
  for(int k0=0; k0<CIN; k0+=KCH){
    if(k0) __syncthreads();
    for(int idx=tid*4; idx<KCH*COUT; idx+=1024){
      int c = idx / COUT, n = idx % COUT;
      float4 w = *(const float4*)(&W[(size_t)(k0+c)*ldw + wofs + n]);
      u16* dst = sW + n*LDA + c;
      dst[0]=f2b(w.x); dst[LDA]=f2b(w.y); dst[2*LDA]=f2b(w.z); dst[3*LDA]=f2b(w.w);
    }
    const int RW = KCH/8;
    for(int g=tid; g<64*RW; g+=256){
      int row = g / RW, c8 = (g % RW)*8;
      *(uint4*)(sA + row*LDA + c8) = *(const uint4*)(in + (size_t)(p0+row)*CIN + k0 + c8);
    }
    __syncthreads();
    #pragma unroll
    for(int kk=0; kk<KCH; kk+=32){
      s8v af = *(const s8v*)(aBase + kk);
      #pragma unroll
      for(int ns=0; ns<NS; ns++){
        s8v bf = *(const s8v*)(wBase + ns*16*LDA + kk);
        acc[ns] = __builtin_amdgcn_mfma_f32_16x16x32_bf16(af, bf, acc[ns], 0, 0, 0);
      }
    }
  }
  int pr = p0 + wv*16 + quad*4;
  #pragma unroll
  for(int ns=0; ns<NS; ns++){
    int n = ns*16 + mrow;
    float bs = bias ? bias[n] : 0.f;
    #pragma unroll
    for(int r=0;r<4;r++){
      float v = acc[ns][r] + bs;
      if(ACT==1) v = leaky02(v);
      else if(ACT==2) v = softplus_(v);
      if(res) v += b2f(res[(size_t)(pr+r)*COUT + n]);
      if(OUTF32) ((float*)outv)[(size_t)(pr+r)*COUT + n] = v;
      else       ((u16*)outv)[(size_t)(pr+r)*COUT + n] = f2b(v);
    }
  }
}

// ====== fused: ssm_in matmul (64->256) + causal dwconv1d(k=4) + silu; no xz ======
__global__ __launch_bounds__(256) void k_mfma_ssm(const float* __restrict__ W,
                     const u16* __restrict__ x0,
                     const float* __restrict__ cw, const float* __restrict__ cb,
                     u16* __restrict__ xi, u16* __restrict__ zs){
  const int CIN=64, COUT=256, LDA=72, NS=16;
  __shared__ __align__(16) u16 sA[64*LDA];     // 9.2 KB
  __shared__ __align__(16) u16 sW[COUT*LDA];   // 36.9 KB
  __shared__ __align__(16) u16 ubuf[67*128];   // 17.2 KB (rows p0-3..p0+63, raw u)
  int tid = threadIdx.x;
  int p0 = blockIdx.x*64;
  int ln = tid & 63, wv = tid >> 6;
  int mrow = ln & 15, quad = ln >> 4;
  for(int idx=tid*4; idx<CIN*COUT; idx+=1024){
    int c = idx / COUT, n = idx % COUT;
    float4 w = *(const float4*)(&W[(size_t)c*COUT + n]);
    u16* dst = sW + n*LDA + c;
    dst[0]=f2b(w.x); dst[LDA]=f2b(w.y); dst[2*LDA]=f2b(w.z); dst[3*LDA]=f2b(w.w);
  }
  for(int g=tid; g<64*8; g+=256){
    int row = g >> 3, c8 = (g & 7)*8;
    *(uint4*)(sA + row*LDA + c8) = *(const uint4*)(x0 + (size_t)(p0+row)*64 + c8);
  }
  __syncthreads();
  f4v acc[NS];
  #pragma unroll
  for(int i=0;i<NS;i++) acc[i] = (f4v){0.f,0.f,0.f,0.f};
  const u16* aBase = sA + (wv*16 + mrow)*LDA + quad*8;
  const u16* wBase = sW + mrow*LDA + quad*8;
  #pragma unroll
  for(int kk=0; kk<CIN; kk+=32){
    s8v af = *(const s8v*)(aBase + kk);
    #pragma unroll
    for(int ns=0; ns<NS; ns++){
      s8v bf = *(const s8v*)(wBase + ns*16*LDA + kk);
      acc[ns] = __builtin_amdgcn_mfma_f32_16x16x32_bf16(af, bf, acc[ns], 0, 0, 0);
    }
  }
  // 3 halo rows of u (VALU dot vs sW); zero at batch starts
  bool bstart = ((p0 & 4095) == 0);
  for(int idx=tid; idx<384; idx+=256){
    int j = idx >> 7, n = idx & 127;
    float a2 = 0.f;
    if(!bstart){
      const u16* xr = x0 + (size_t)(p0-3+j)*64;
      #pragma unroll 8
      for(int c=0;c<64;c++) a2 += b2f(xr[c]) * b2f(sW[n*LDA+c]);
    }
    ubuf[j*128 + n] = f2b(a2);
  }
  // epilogue: u -> ubuf (raw), z -> silu -> zs
  int prl = wv*16 + quad*4;
  #pragma unroll
  for(int ns=0; ns<NS; ns++){
    int n = ns*16 + mrow;
    if(n < 128){
      #pragma unroll
      for(int r=0;r<4;r++) ubuf[(prl+r+3)*128 + n] = f2b(acc[ns][r]);
    }else{
      #pragma unroll
      for(int r=0;r<4;r++) zs[(size_t)(p0+prl+r)*128 + (n-128)] = f2b(silu_(acc[ns][r]));
    }
  }
  __syncthreads();
  // causal conv + silu -> xi
  int d4 = tid & 31;
  float4 cbv = *(const float4*)(cb + d4*4);
  for(int row = tid >> 5; row < 64; row += 8){
    float a0=cbv.x, a1=cbv.y, a2=cbv.z, a3=cbv.w;
    #pragma unroll
    for(int k=0;k<4;k++){
      ushort4 v = *(const ushort4*)(ubuf + (row+k)*128 + d4*4);
      float4 wv4 = *(const float4*)(cw + k*128 + d4*4);
      a0 += b2f(v.x)*wv4.x; a1 += b2f(v.y)*wv4.y;
      a2 += b2f(v.z)*wv4.z; a3 += b2f(v.w)*wv4.w;
    }
    ushort4 o; o.x=f2b(silu_(a0)); o.y=f2b(silu_(a1)); o.z=f2b(silu_(a2)); o.w=f2b(silu_(a3));
    *(ushort4*)(xi + (size_t)(p0+row)*128 + d4*4) = o;
  }
}

// ====== fused: dt/bc MFMA ([128]@[128,160]) + scan phase 1 (4 chunks/block) ======
__global__ __launch_bounds__(256) void k_dtbc_scan(const float* __restrict__ W2,
                     const u16* __restrict__ in, const float* __restrict__ dtbias,
                     const float* __restrict__ alog,
                     u16* __restrict__ dtout, u16* __restrict__ bcout,
                     u16* __restrict__ Pb, u16* __restrict__ Qb){
  const int CIN=128, COUT=160, LDA=136, NS=10;
  __shared__ __align__(16) u16 sA[64*LDA];     // xi tile — reused by scan
  __shared__ __align__(16) u16 sW[COUT*LDA];   // aliased to sdt/sbc after MFMA
  u16* sdt = sW;                // 64*128
  u16* sbc = sW + 64*128;       // 64*32
  int tid = threadIdx.x;
  int p0 = blockIdx.x * 64;
  int ln = tid & 63, wv = tid >> 6;
  int mrow = ln & 15, quad = ln >> 4;
  for(int idx=tid*4; idx<CIN*COUT; idx+=1024){
    int c = idx / COUT, n = idx % COUT;
    float4 w = *(const float4*)(&W2[(size_t)c*COUT + n]);
    u16* dst = sW + n*LDA + c;
    dst[0]=f2b(w.x); dst[LDA]=f2b(w.y); dst[2*LDA]=f2b(w.z); dst[3*LDA]=f2b(w.w);
  }
  for(int g=tid; g<64*16; g+=256){
    int row = g >> 4, c8 = (g & 15)*8;
    *(uint4*)(sA + row*LDA + c8) = *(const uint4*)(in + (size_t)(p0+row)*CIN + c8);
  }
  __syncthreads();
  f4v acc[NS];
  #pragma unroll
  for(int i=0;i<NS;i++) acc[i] = (f4v){0.f,0.f,0.f,0.f};
  const u16* aBase = sA + (wv*16 + mrow)*LDA + quad*8;
  const u16* wBase = sW + mrow*LDA + quad*8;
  #pragma unroll
  for(int kk=0; kk<CIN; kk+=32){
    s8v af = *(const s8v*)(aBase + kk);
    #pragma unroll
    for(int ns=0; ns<NS; ns++){
      s8v bf = *(const s8v*)(wBase + ns*16*LDA + kk);
      acc[ns] = __builtin_amdgcn_mfma_f32_16x16x32_bf16(af, bf, acc[ns], 0, 0, 0);
    }
  }
  __syncthreads();   // done reading sW; safe to alias sdt/sbc
  int pr = p0 + wv*16 + quad*4;
  int prl = wv*16 + quad*4;
  #pragma unroll
  for(int ns=0; ns<NS; ns++){
    int n = ns*16 + mrow;
    if(n < 128){
      float bs = dtbias[n];
      #pragma unroll
      for(int r=0;r<4;r++){
        u16 v = f2b(softplus_(acc[ns][r] + bs));
        dtout[(size_t)(pr+r)*128 + n] = v;
        sdt[(prl+r)*128 + n] = v;
      }
    }else{
      #pragma unroll
      for(int r=0;r<4;r++){
        u16 v = f2b(acc[ns][r]);
        bcout[(size_t)(pr+r)*32 + (n-128)] = v;
        sbc[(prl+r)*32 + (n-128)] = v;
      }
    }
  }
  __syncthreads();
  // scan phase 1 over the block's 4 chunks (CHL=16)
  int d = tid & 127;
  int b = p0 >> 12;
  int chb = (blockIdx.x & 63)*4;
  float A[16];
  #pragma unroll
  for(int s=0;s<16;s++) A[s] = -__expf(alog[d*16+s]);
  for(int cl = tid >> 7; cl < 4; cl += 2){
    float P[16], Q[16];
    #pragma unroll
    for(int s=0;s<16;s++){ P[s]=1.f; Q[s]=0.f; }
    #pragma unroll
    for(int i=0;i<CHL;i++){
      float dtv = b2f(sdt[(cl*16+i)*128 + d]);
      float xiv = b2f(sA[(cl*16+i)*LDA + d]);
      float u = dtv*xiv;
      #pragma unroll
      for(int s=0;s<16;s++){
        float a = __expf(dtv*A[s]);
        P[s] *= a;
        Q[s] = a*Q[s] + u*b2f(sbc[(cl*16+i)*32+s]);
      }
    }
    int gidx = (chb+cl)*16384 + (b*128+d)*16;
    unsigned pw[8], qw[8];
    #pragma unroll
    for(int j=0;j<8;j++){
      pw[j] = (unsigned)f2b(P[2*j]) | ((unsigned)f2b(P[2*j+1])<<16);
      qw[j] = (unsigned)f2b(Q[2*j]) | ((unsigned)f2b(Q[2*j+1])<<16);
    }
    *(uint4*)(Pb+gidx)   = make_uint4(pw[0],pw[1],pw[2],pw[3]);
    *(uint4*)(Pb+gidx+8) = make_uint4(pw[4],pw[5],pw[6],pw[7]);
    *(uint4*)(Qb+gidx)   = make_uint4(qw[0],qw[1],qw[2],qw[3]);
    *(uint4*)(Qb+gidx+8) = make_uint4(qw[4],qw[5],qw[6],qw[7]);
  }
}

// ========== MFMA with fused LayerNorm on A (CIN=64) ==========
template<int COUT, int ACT>
__global__ __launch_bounds__(256) void k_mfma_ln(const float* __restrict__ W, int ldw,
                     const u16* __restrict__ in, const float* __restrict__ g,
                     const float* __restrict__ bta, u16* __restrict__ outp){
  const int CIN = 64, LDA = 72, NS = COUT/16;
  __shared__ __align__(16) u16 sA[64*LDA];
  __shared__ __align__(16) u16 sW[COUT*LDA];
  int tid = threadIdx.x;
  int p0 = blockIdx.x * 64;
  int ln = tid & 63, wv = tid >> 6;
  int mrow = ln & 15, quad = ln >> 4;
  for(int idx=tid*4; idx<CIN*COUT; idx+=1024){
    int c = idx / COUT, n = idx % COUT;
    float4 w = *(const float4*)(&W[(size_t)c*ldw + n]);
    u16* dst = sW + n*LDA + c;
    dst[0]=f2b(w.x); dst[LDA]=f2b(w.y); dst[2*LDA]=f2b(w.z); dst[3*LDA]=f2b(w.w);
  }
  float gg = g[ln], bb = bta[ln];
  #pragma unroll
  for(int i=0;i<16;i++){
    int row = wv*16 + i;
    float v = b2f(in[(size_t)(p0+row)*64 + ln]);
    float s = v, sq = v*v;
    #pragma unroll
    for(int o=32;o>0;o>>=1){ s += __shfl_xor(s,o); sq += __shfl_xor(sq,o); }
    float m = s*(1.f/64.f);
    float var = sq*(1.f/64.f) - m*m;
    float r = rsqrtf(var + 1e-5f);
    sA[row*LDA + ln] = f2b((v-m)*r*gg + bb);
  }
  __syncthreads();
  f4v acc[NS];
  #pragma unroll
  for(int i=0;i<NS;i++) acc[i] = (f4v){0.f,0.f,0.f,0.f};
  const u16* aBase = sA + (wv*16 + mrow)*LDA + quad*8;
  const u16* wBase = sW + mrow*LDA + quad*8;
  #pragma unroll
  for(int kk=0; kk<CIN; kk+=32){
    s8v af = *(const s8v*)(aBase + kk);
    #pragma unroll
    for(int ns=0; ns<NS; ns++){
      s8v bf = *(const s8v*)(wBase + ns*16*LDA + kk);
      acc[ns] = __builtin_amdgcn_mfma_f32_16x16x32_bf16(af, bf, acc[ns], 0, 0, 0);
    }
  }
  int pr = p0 + wv*16 + quad*4;
  #pragma unroll
  for(int ns=0; ns<NS; ns++){
    int n = ns*16 + mrow;
    #pragma unroll
    for(int r=0;r<4;r++){
      float v = acc[ns][r];
      if(ACT==1) v = leaky02(v);
      outp[(size_t)(pr+r)*COUT + n] = f2b(v);
    }
  }
}

// ========== final MFMA: [NPIX,256] @ [256,64] + res, fp32 NCHW store ==========
__global__ __launch_bounds__(256) void k_mfma_fin(const float* __restrict__ W,
                     const u16* __restrict__ in, const u16* __restrict__ res,
                     float* __restrict__ outp){
  const int CIN=256, COUT=64, KCH=128, LDA=136, NS=4;
  __shared__ __align__(16) u16 sA[64*LDA];
  __shared__ __align__(16) u16 sW[COUT*LDA];
  int tid = threadIdx.x;
  int p0 = blockIdx.x * 64;
  int ln = tid & 63, wv = tid >> 6;
  int mrow = ln & 15, quad = ln >> 4;
  f4v acc[NS];
  #pragma unroll
  for(int i=0;i<NS;i++) acc[i] = (f4v){0.f,0.f,0.f,0.f};
  const u16* aBase = sA + (wv*16 + mrow)*LDA + quad*8;
  const u16* wBase = sW + mrow*LDA + quad*8;
  for(int k0=0; k0<CIN; k0+=KCH){
    if(k0) __syncthreads();
    for(int idx=tid*4; idx<KCH*COUT; idx+=1024){
      int c = idx / COUT, n = idx % COUT;
      float4 w = *(const float4*)(&W[(size_t)(k0+c)*COUT + n]);
      u16* dst = sW + n*LDA + c;
      dst[0]=f2b(w.x); dst[LDA]=f2b(w.y); dst[2*LDA]=f2b(w.z); dst[3*LDA]=f2b(w.w);
    }
    for(int g=tid; g<64*16; g+=256){
      int row = g >> 4, c8 = (g & 15)*8;
      *(uint4*)(sA + row*LDA + c8) = *(const uint4*)(in + (size_t)(p0+row)*CIN + k0 + c8);
    }
    __syncthreads();
    #pragma unroll
    for(int kk=0; kk<KCH; kk+=32){
      s8v af = *(const s8v*)(aBase + kk);
      #pragma unroll
      for(int ns=0; ns<NS; ns++){
        s8v bf = *(const s8v*)(wBase + ns*16*LDA + kk);
        acc[ns] = __builtin_amdgcn_mfma_f32_16x16x32_bf16(af, bf, acc[ns], 0, 0, 0);
      }
    }
  }
  int pr = p0 + wv*16 + quad*4;
  int b = blockIdx.x >> 6;
  int hwr = ((blockIdx.x & 63) << 6) + wv*16 + quad*4;
  #pragma unroll
  for(int ns=0; ns<NS; ns++){
    int n = ns*16 + mrow;
    float4 v4;
    v4.x = acc[ns][0] + b2f(res[(size_t)(pr+0)*64 + n]);
    v4.y = acc[ns][1] + b2f(res[(size_t)(pr+1)*64 + n]);
    v4.z = acc[ns][2] + b2f(res[(size_t)(pr+2)*64 + n]);
    v4.w = acc[ns][3] + b2f(res[(size_t)(pr+3)*64 + n]);
    *(float4*)(outp + (size_t)b*C_*HW_ + (size_t)n*HW_ + hwr) = v4;
  }
}

// ---------------- depthwise 3x3 SAME, 4 channels per thread ----------------
template<int CN, int ACT>   // ACT: 0 none, 1 leaky, 2 gelu
__global__ void k_dw3(const u16* __restrict__ in, const float* __restrict__ wgt,
                      const u16* __restrict__ res1, const u16* __restrict__ res2,
                      u16* __restrict__ out){
  const int C4 = CN/4;
  int g = blockIdx.x*256 + threadIdx.x;
  int c4 = g % C4;
  int pix = g / C4;
  int w = pix & 63;
  int h = (pix >> 6) & 63;
  int b = pix >> 12;
  float a0=0.f, a1=0.f, a2=0.f, a3=0.f;
  #pragma unroll
  for(int kh=0;kh<3;kh++){
    int hh = h + kh - 1;
    if((unsigned)hh < 64u){
      #pragma unroll
      for(int kw=0;kw<3;kw++){
        int ww = w + kw - 1;
        if((unsigned)ww < 64u){
          ushort4 v = *(const ushort4*)(in + (size_t)((b*64+hh)*64 + ww)*CN + c4*4);
          float4 wv = *(const float4*)(wgt + (kh*3+kw)*CN + c4*4);
          a0 += b2f(v.x)*wv.x; a1 += b2f(v.y)*wv.y;
          a2 += b2f(v.z)*wv.z; a3 += b2f(v.w)*wv.w;
        }
      }
    }
  }
  if(ACT==1){ a0=leaky02(a0); a1=leaky02(a1); a2=leaky02(a2); a3=leaky02(a3); }
  else if(ACT==2){ a0=gelu_exact(a0); a1=gelu_exact(a1); a2=gelu_exact(a2); a3=gelu_exact(a3); }
  size_t ob = (size_t)pix*CN + c4*4;
  if(res1){ ushort4 r = *(const ushort4*)(res1 + ob);
            a0+=b2f(r.x); a1+=b2f(r.y); a2+=b2f(r.z); a3+=b2f(r.w); }
  if(res2){ ushort4 r = *(const ushort4*)(res2 + ob);
            a0+=b2f(r.x); a1+=b2f(r.y); a2+=b2f(r.z); a3+=b2f(r.w); }
  ushort4 o; o.x=f2b(a0); o.y=f2b(a1); o.z=f2b(a2); o.w=f2b(a3);
  *(ushort4*)(out + ob) = o;
}

// ------- build combined W2 [128][160] -------
__global__ void k_fusew2(const float* __restrict__ xproj, const float* __restrict__ dtw,
                         float* __restrict__ w2){
  int g = blockIdx.x*256 + threadIdx.x;     // 20480
  if(g >= 20480) return;
  int n = g % 160;
  int c = g / 160;
  float v;
  if(n < 128){
    v = 0.f;
    #pragma unroll
    for(int r=0;r<4;r++) v += xproj[c*36 + r] * dtw[r*128 + n];
  }else{
    v = xproj[c*36 + 4 + (n-128)];
  }
  w2[c*160 + n] = v;
}

// ---------------- scan phase 2 ----------------
__global__ void k_scan2(const u16* __restrict__ Pb, const u16* __restrict__ Qb,
                        u16* __restrict__ Hin){
  int g = blockIdx.x*64 + threadIdx.x;     // 16384 = (b,d,s)
  float h = 0.f;
  #pragma unroll 8
  for(int ch=0; ch<NCH; ch++){
    Hin[ch*16384 + g] = f2b(h);
    h = b2f(Pb[ch*16384 + g])*h + b2f(Qb[ch*16384 + g]);
  }
}

// ------- scan phase 3 (yss in-place over dt) -------
__global__ __launch_bounds__(128) void k_scan3(const u16* __restrict__ dt, const u16* __restrict__ xi,
                        const u16* __restrict__ bc, const u16* __restrict__ zs,
                        const float* __restrict__ alog, const float* __restrict__ Dp,
                        const u16* __restrict__ Hin, u16* __restrict__ yss){
  int blk = blockIdx.x;         // 2048 blocks of 128
  int ch = blk & (NCH-1);
  int b = blk >> 8;
  int d = threadIdx.x;
  __shared__ __align__(16) u16 sdt[CHL*128], sxi[CHL*128], szs[CHL*128], sbc[CHL*32];
  float A[16], h[16];
  u16 hbuf[16];
  int gidx = ch*16384 + (b*128+d)*16;
  *(uint4*)hbuf     = *(const uint4*)(Hin+gidx);
  *(uint4*)(hbuf+8) = *(const uint4*)(Hin+gidx+8);
  #pragma unroll
  for(int s=0;s<16;s++){ A[s] = -__expf(alog[d*16+s]); h[s] = b2f(hbuf[s]); }
  float Dd = Dp[d];
  int pbase = b*HW_ + ch*CHL;
  const uint4* gdt = (const uint4*)(dt + (size_t)pbase*128);
  const uint4* gxi = (const uint4*)(xi + (size_t)pbase*128);
  const uint4* gzs = (const uint4*)(zs + (size_t)pbase*128);
  ((uint4*)sdt)[d]     = gdt[d];
  ((uint4*)sdt)[d+128] = gdt[d+128];
  ((uint4*)sxi)[d]     = gxi[d];
  ((uint4*)sxi)[d+128] = gxi[d+128];
  ((uint4*)szs)[d]     = gzs[d];
  ((uint4*)szs)[d+128] = gzs[d+128];
  if(d < 64) ((uint4*)sbc)[d] = ((const uint4*)(bc + (size_t)pbase*32))[d];
  __syncthreads();
  #pragma unroll
  for(int i=0;i<CHL;i++){
    float dtv = b2f(sdt[i*128+d]);
    float xiv = b2f(sxi[i*128+d]);
    float u = dtv*xiv;
    float acc = Dd*xiv;
    #pragma unroll
    for(int s=0;s<16;s++){
      float a = __expf(dtv*A[s]);
      h[s] = a*h[s] + u*b2f(sbc[i*32+s]);
      acc += h[s]*b2f(sbc[i*32+16+s]);
    }
    yss[(size_t)(pbase+i)*128 + d] = f2b(acc * b2f(szs[i*128+d]));
  }
}

extern "C" void kernel_launch(void* const* d_in, const int* in_sizes, int n_in,
                              void* d_out, int out_size, void* d_ws, size_t ws_size,
                              hipStream_t stream) {
  const float* x        = (const float*)d_in[0];
  const float* ln1_g    = (const float*)d_in[1];
  const float* ln1_b    = (const float*)d_in[2];
  const float* vin_w1   = (const float*)d_in[3];
  const float* vin_dw   = (const float*)d_in[4];
  const float* vin_w2   = (const float*)d_in[5];
  const float* vout_dw1 = (const float*)d_in[6];
  const float* vout_dw2 = (const float*)d_in[7];
  const float* ssm_in_w = (const float*)d_in[8];
  const float* ssm_cw   = (const float*)d_in[9];
  const float* ssm_cb   = (const float*)d_in[10];
  const float* ssm_xprj = (const float*)d_in[11];
  const float* ssm_dtw  = (const float*)d_in[12];
  const float* ssm_dtb  = (const float*)d_in[13];
  const float* ssm_Alog = (const float*)d_in[14];
  const float* ssm_D    = (const float*)d_in[15];
  const float* ssm_outw = (const float*)d_in[16];
  const float* ln2_g    = (const float*)d_in[17];
  const float* ln2_b    = (const float*)d_in[18];
  const float* ff_w1    = (const float*)d_in[19];
  const float* ff_dw    = (const float*)d_in[20];
  const float* ff_w2    = (const float*)d_in[21];
  float* out = (float*)d_out;

  // ---- bf16 arena, lifetime-packed (units: bf16 elements) ----
  const size_t M = 1u<<20;
  u16* U   = (u16*)d_ws;
  u16* xT  = U;              // [0,2M)    lives to vision-out residual
  u16* tA  = U + 2*M;        // [2M,4M)   } Hin here during scan
  u16* tB  = U + 4*M;        // [4M,6M)   }
  u16* x0  = U + 6*M;        // [6M,8M)   x0, later xR
  u16* xi  = U + 8*M;        // [8M,12M)  xi; first 2M later reused as y
  u16* zs  = U + 12*M;       // [12M,16M) silu(z)
  u16* xz  = U + 16*M;       // [16M,24M) Pb/Qb during scan; later t1
  u16* dtb = U + 24*M;       // [24M,28M) dt; scan3 writes yss in-place; later t2 start
  u16* bc  = U + 28*M;       // [28M,29M)
  float* wf2 = (float*)(U + 29*M);   // 20480 floats spare
  u16* Pb  = U + 16*M;       // [16M,20M)
  u16* Qb  = U + 20*M;       // [20M,24M)
  u16* Hin = tA;             // [2M,6M)
  u16* yss = dtb;            // in-place over dt
  u16* y   = xi;             // (xi free after scan3)
  u16* t2  = dtb;            // [24M,32M)

  k_fusew2<<<80,256,0,stream>>>(ssm_xprj, ssm_dtw, wf2);

  // --- vision in path ---
  k_trans_ln_mm<<<512,256,0,stream>>>(x, ln1_g, ln1_b, vin_w1, xT, tB);
  k_dw3<64,2><<<2048,256,0,stream>>>(tB, vin_dw, nullptr, nullptr, tA);
  k_mfma<64,64,0,false><<<512,256,0,stream>>>(vin_w2, 64, 0, tA, nullptr, nullptr, x0);

  // --- SSM ---
  k_mfma_ssm<<<512,256,0,stream>>>(ssm_in_w, x0, ssm_cw, ssm_cb, xi, zs);
  k_dtbc_scan<<<512,256,0,stream>>>(wf2, xi, ssm_dtb, ssm_Alog, dtb, bc, Pb, Qb);
  k_scan2<<<256,64,0,stream>>>(Pb, Qb, Hin);
  k_scan3<<<2048,128,0,stream>>>(dtb, xi, bc, zs, ssm_Alog, ssm_D, Hin, yss);
  k_mfma<128,64,0,false><<<512,256,0,stream>>>(ssm_outw, 64, 0, yss, nullptr, x0, y); // y = ssm + x0

  // --- vision out path:  xR = dw2(gelu(dw1(y))) + y + xT ---
  k_dw3<64,2><<<2048,256,0,stream>>>(y, vout_dw1, nullptr, nullptr, tA);
  k_dw3<64,0><<<2048,256,0,stream>>>(tA, vout_dw2, y, xT, x0);   // x0 now = xR

  // --- FFN (LN fused into ff_w1; trans_out fused into ff_w2) ---
  k_mfma_ln<256,1><<<512,256,0,stream>>>(ff_w1, 256, x0, ln2_g, ln2_b, xz);  // t1
  k_dw3<256,1><<<8192,256,0,stream>>>(xz, ff_dw, nullptr, nullptr, t2);
  k_mfma_fin<<<512,256,0,stream>>>(ff_w2, t2, x0, out);
}

// Round 10
// 294.553 us; speedup vs baseline: 3.7466x; 1.0624x over previous
//
#include <hip/hip_runtime.h>
#include <hip/hip_bf16.h>
#include <math.h>

typedef unsigned short u16;   // bf16 storage
typedef __attribute__((ext_vector_type(8))) short s8v;    // 8 bf16 = 4 VGPR
typedef __attribute__((ext_vector_type(4))) float f4v;    // MFMA acc

#define B_    8
#define C_    64
#define HW_   4096
#define NPIX  32768     // B_*HW_
#define DI    128
#define NCH   256
#define CHL   16        // HW_/NCH

__device__ __forceinline__ float b2f(u16 v){ return __uint_as_float(((unsigned)v)<<16); }
__device__ __forceinline__ u16 f2b(float x){
  unsigned u = __float_as_uint(x);
  u += 0x7fff + ((u >> 16) & 1);      // RTNE
  return (u16)(u >> 16);
}
__device__ __forceinline__ float gelu_exact(float x){ return 0.5f*x*(1.0f+erff(x*0.70710678118654752f)); }
__device__ __forceinline__ float leaky02(float x){ return x>0.f ? x : 0.2f*x; }
__device__ __forceinline__ float softplus_(float x){ return fmaxf(x,0.f)+log1pf(__expf(-fabsf(x))); }
__device__ __forceinline__ float silu_(float x){ return x / (1.0f + __expf(-x)); }

// ====== prep: all weights -> bf16 transposed [COUT][CIN]; W2 fused (xproj/dtw) ======
__global__ void k_prep(const float* __restrict__ vin_w1, const float* __restrict__ vin_w2,
                       const float* __restrict__ ssm_in_w, const float* __restrict__ xproj,
                       const float* __restrict__ dtw, const float* __restrict__ ssm_outw,
                       const float* __restrict__ ff_w1, const float* __restrict__ ff_w2,
                       u16* __restrict__ wv1, u16* __restrict__ wv2, u16* __restrict__ wsi,
                       u16* __restrict__ wdb, u16* __restrict__ wout, u16* __restrict__ wf1,
                       u16* __restrict__ wf2t){
  int g = blockIdx.x*256 + threadIdx.x;     // 80*256 = 20480
  if(g < 4096){
    int n=g>>6, c=g&63;
    wv1[n*64+c]=f2b(vin_w1[c*64+n]);
    wv2[n*64+c]=f2b(vin_w2[c*64+n]);
  }
  if(g < 16384){
    int n=g>>6, c=g&63;
    wsi[n*64+c]=f2b(ssm_in_w[c*256+n]);
    wf1[n*64+c]=f2b(ff_w1[c*256+n]);
    int n2=g/256, k2=g%256;
    wf2t[n2*256+k2]=f2b(ff_w2[k2*64+n2]);
  }
  if(g < 8192){
    int n=g>>7, k=g&127;
    wout[n*128+k]=f2b(ssm_outw[k*64+n]);
  }
  if(g < 20480){
    int n=g/128, k=g%128;
    float v;
    if(n < 128){
      v = 0.f;
      for(int r=0;r<4;r++) v += xproj[k*36+r]*dtw[r*128+n];
    }else{
      v = xproj[k*36+4+(n-128)];
    }
    wdb[n*128+k]=f2b(v);
  }
}

// ====== fused: NCHW fp32 -> (xT bf16 NHWC) + LayerNorm + vin_w1 MFMA -> outp ======
__global__ __launch_bounds__(256) void k_trans_ln_mm(const float* __restrict__ x,
                     const float* __restrict__ g, const float* __restrict__ bta,
                     const u16* __restrict__ wT,
                     u16* __restrict__ xT, u16* __restrict__ outp){
  const int LDA = 72, NS = 4;
  __shared__ float tile[64][65];
  __shared__ __align__(16) u16 sA[64*LDA];
  __shared__ __align__(16) u16 sW[64*LDA];
  int tid = threadIdx.x;
  int blk = blockIdx.x;            // 512
  int b = blk >> 6;
  int hwb = (blk & 63) << 6;
  int lane = tid & 63, row = tid >> 6;
  const float* src = x + (size_t)b*C_*HW_;
  #pragma unroll
  for(int k=0;k<16;k++){
    int c = row + 4*k;
    tile[c][lane] = src[c*HW_ + hwb + lane];
  }
  for(int idx=tid; idx<64*8; idx+=256){
    int n = idx>>3, c8 = (idx&7)*8;
    *(uint4*)(sW + n*LDA + c8) = *(const uint4*)(wT + n*64 + c8);
  }
  __syncthreads();
  u16* dstT = xT + (size_t)b*HW_*C_;
  #pragma unroll
  for(int k=0;k<16;k++){
    int hwl = row + 4*k;
    dstT[(hwb+hwl)*C_ + lane] = f2b(tile[lane][hwl]);
  }
  float gg = g[lane], bb = bta[lane];
  #pragma unroll
  for(int i=0;i<16;i++){
    int hwl = row*16 + i;
    float v = tile[lane][hwl];
    float s = v, sq = v*v;
    #pragma unroll
    for(int o=32;o>0;o>>=1){ s += __shfl_xor(s,o); sq += __shfl_xor(sq,o); }
    float m = s*(1.f/64.f);
    float var = sq*(1.f/64.f) - m*m;
    float r = rsqrtf(var + 1e-5f);
    sA[hwl*LDA + lane] = f2b((v-m)*r*gg + bb);
  }
  __syncthreads();
  int ln = tid & 63, wv = tid >> 6;
  int mrow = ln & 15, quad = ln >> 4;
  f4v acc[NS];
  #pragma unroll
  for(int i=0;i<NS;i++) acc[i] = (f4v){0.f,0.f,0.f,0.f};
  const u16* aBase = sA + (wv*16 + mrow)*LDA + quad*8;
  const u16* wBase = sW + mrow*LDA + quad*8;
  #pragma unroll
  for(int kk=0; kk<64; kk+=32){
    s8v af = *(const s8v*)(aBase + kk);
    #pragma unroll
    for(int ns=0; ns<NS; ns++){
      s8v bf = *(const s8v*)(wBase + ns*16*LDA + kk);
      acc[ns] = __builtin_amdgcn_mfma_f32_16x16x32_bf16(af, bf, acc[ns], 0, 0, 0);
    }
  }
  int p0 = blk*64;
  int pr = p0 + wv*16 + quad*4;
  #pragma unroll
  for(int ns=0; ns<NS; ns++){
    int n = ns*16 + mrow;
    #pragma unroll
    for(int r=0;r<4;r++)
      outp[(size_t)(pr+r)*64 + n] = f2b(acc[ns][r]);
  }
}

// ========== generic MFMA matmul: [NPIX,CIN](bf16) @ wT[COUT][CIN](bf16) ==========
template<int CIN, int COUT, int ACT, bool OUTF32>
__global__ __launch_bounds__(256) void k_mfma(const u16* __restrict__ wT,
                     const u16* __restrict__ in, const float* __restrict__ bias,
                     const u16* __restrict__ res, void* __restrict__ outv){
  const int KCH = (CIN < 128) ? CIN : 128;
  const int LDA = KCH + 8;
  const int NS  = COUT / 16;
  __shared__ __align__(16) u16 sA[64*LDA];
  __shared__ __align__(16) u16 sW[COUT*LDA];
  int tid = threadIdx.x;
  int p0 = blockIdx.x * 64;
  int ln = tid & 63, wv = tid >> 6;
  int mrow = ln & 15, quad = ln >> 4;
  f4v acc[NS];
  #pragma unroll
  for(int i=0;i<NS;i++) acc[i] = (f4v){0.f,0.f,0.f,0.f};
  const u16* aBase = sA + (wv*16 + mrow)*LDA + quad*8;
  const u16* wBase = sW + mrow*LDA + quad*8;
  const int RW = KCH/8;
  for(int k0=0; k0<CIN; k0+=KCH){
    if(k0) __syncthreads();
    for(int idx=tid; idx<COUT*RW; idx+=256){
      int n = idx/RW, c8 = (idx%RW)*8;
      *(uint4*)(sW + n*LDA + c8) = *(const uint4*)(wT + (size_t)n*CIN + k0 + c8);
    }
    for(int g=tid; g<64*RW; g+=256){
      int row = g / RW, c8 = (g % RW)*8;
      *(uint4*)(sA + row*LDA + c8) = *(const uint4*)(in + (size_t)(p0+row)*CIN + k0 + c8);
    }
    __syncthreads();
    #pragma unroll
    for(int kk=0; kk<KCH; kk+=32){
      s8v af = *(const s8v*)(aBase + kk);
      #pragma unroll
      for(int ns=0; ns<NS; ns++){
        s8v bf = *(const s8v*)(wBase + ns*16*LDA + kk);
        acc[ns] = __builtin_amdgcn_mfma_f32_16x16x32_bf16(af, bf, acc[ns], 0, 0, 0);
      }
    }
  }
  int pr = p0 + wv*16 + quad*4;
  #pragma unroll
  for(int ns=0; ns<NS; ns++){
    int n = ns*16 + mrow;
    float bs = bias ? bias[n] : 0.f;
    #pragma unroll
    for(int r=0;r<4;r++){
      float v = acc[ns][r] + bs;
      if(ACT==1) v = leaky02(v);
      else if(ACT==2) v = softplus_(v);
      if(res) v += b2f(res[(size_t)(pr+r)*COUT + n]);
      if(OUTF32) ((float*)outv)[(size_t)(pr+r)*COUT + n] = v;
      else       ((u16*)outv)[(size_t)(pr+r)*COUT + n] = f2b(v);
    }
  }
}

// ====== fused: ssm_in matmul (64->256) + causal dwconv1d(k=4) + silu; no xz ======
__global__ __launch_bounds__(256) void k_mfma_ssm(const u16* __restrict__ wT,
                     const u16* __restrict__ x0,
                     const float* __restrict__ cw, const float* __restrict__ cb,
                     u16* __restrict__ xi, u16* __restrict__ zs){
  const int CIN=64, COUT=256, LDA=72, NS=16;
  __shared__ __align__(16) u16 sA[64*LDA];
  __shared__ __align__(16) u16 sW[COUT*LDA];
  __shared__ __align__(16) u16 ubuf[67*128];
  int tid = threadIdx.x;
  int p0 = blockIdx.x*64;
  int ln = tid & 63, wv = tid >> 6;
  int mrow = ln & 15, quad = ln >> 4;
  for(int idx=tid; idx<COUT*8; idx+=256){
    int n = idx>>3, c8 = (idx&7)*8;
    *(uint4*)(sW + n*LDA + c8) = *(const uint4*)(wT + n*64 + c8);
  }
  for(int g=tid; g<64*8; g+=256){
    int row = g >> 3, c8 = (g & 7)*8;
    *(uint4*)(sA + row*LDA + c8) = *(const uint4*)(x0 + (size_t)(p0+row)*64 + c8);
  }
  __syncthreads();
  f4v acc[NS];
  #pragma unroll
  for(int i=0;i<NS;i++) acc[i] = (f4v){0.f,0.f,0.f,0.f};
  const u16* aBase = sA + (wv*16 + mrow)*LDA + quad*8;
  const u16* wBase = sW + mrow*LDA + quad*8;
  #pragma unroll
  for(int kk=0; kk<CIN; kk+=32){
    s8v af = *(const s8v*)(aBase + kk);
    #pragma unroll
    for(int ns=0; ns<NS; ns++){
      s8v bf = *(const s8v*)(wBase + ns*16*LDA + kk);
      acc[ns] = __builtin_amdgcn_mfma_f32_16x16x32_bf16(af, bf, acc[ns], 0, 0, 0);
    }
  }
  // 3 halo rows of u (VALU dot vs sW); zero at batch starts
  bool bstart = ((p0 & 4095) == 0);
  for(int idx=tid; idx<384; idx+=256){
    int j = idx >> 7, n = idx & 127;
    float a2 = 0.f;
    if(!bstart){
      const u16* xr = x0 + (size_t)(p0-3+j)*64;
      #pragma unroll 8
      for(int c=0;c<64;c++) a2 += b2f(xr[c]) * b2f(sW[n*LDA+c]);
    }
    ubuf[j*128 + n] = f2b(a2);
  }
  int prl = wv*16 + quad*4;
  #pragma unroll
  for(int ns=0; ns<NS; ns++){
    int n = ns*16 + mrow;
    if(n < 128){
      #pragma unroll
      for(int r=0;r<4;r++) ubuf[(prl+r+3)*128 + n] = f2b(acc[ns][r]);
    }else{
      #pragma unroll
      for(int r=0;r<4;r++) zs[(size_t)(p0+prl+r)*128 + (n-128)] = f2b(silu_(acc[ns][r]));
    }
  }
  __syncthreads();
  int d4 = tid & 31;
  float4 cbv = *(const float4*)(cb + d4*4);
  for(int row = tid >> 5; row < 64; row += 8){
    float a0=cbv.x, a1=cbv.y, a2=cbv.z, a3=cbv.w;
    #pragma unroll
    for(int k=0;k<4;k++){
      ushort4 v = *(const ushort4*)(ubuf + (row+k)*128 + d4*4);
      float4 wv4 = *(const float4*)(cw + k*128 + d4*4);
      a0 += b2f(v.x)*wv4.x; a1 += b2f(v.y)*wv4.y;
      a2 += b2f(v.z)*wv4.z; a3 += b2f(v.w)*wv4.w;
    }
    ushort4 o; o.x=f2b(silu_(a0)); o.y=f2b(silu_(a1)); o.z=f2b(silu_(a2)); o.w=f2b(silu_(a3));
    *(ushort4*)(xi + (size_t)(p0+row)*128 + d4*4) = o;
  }
}

// ====== fused: dt/bc MFMA ([128]@wdb[160][128]) + scan phase 1 (4 chunks/block) ======
__global__ __launch_bounds__(256) void k_dtbc_scan(const u16* __restrict__ wT,
                     const u16* __restrict__ in, const float* __restrict__ dtbias,
                     const float* __restrict__ alog,
                     u16* __restrict__ dtout, u16* __restrict__ bcout,
                     u16* __restrict__ Pb, u16* __restrict__ Qb){
  const int CIN=128, COUT=160, LDA=136, NS=10;
  __shared__ __align__(16) u16 sA[64*LDA];
  __shared__ __align__(16) u16 sW[COUT*LDA];
  u16* sdt = sW;                // 64*128
  u16* sbc = sW + 64*128;       // 64*32
  int tid = threadIdx.x;
  int p0 = blockIdx.x * 64;
  int ln = tid & 63, wv = tid >> 6;
  int mrow = ln & 15, quad = ln >> 4;
  for(int idx=tid; idx<COUT*16; idx+=256){
    int n = idx>>4, c8 = (idx&15)*8;
    *(uint4*)(sW + n*LDA + c8) = *(const uint4*)(wT + n*128 + c8);
  }
  for(int g=tid; g<64*16; g+=256){
    int row = g >> 4, c8 = (g & 15)*8;
    *(uint4*)(sA + row*LDA + c8) = *(const uint4*)(in + (size_t)(p0+row)*128 + c8);
  }
  __syncthreads();
  f4v acc[NS];
  #pragma unroll
  for(int i=0;i<NS;i++) acc[i] = (f4v){0.f,0.f,0.f,0.f};
  const u16* aBase = sA + (wv*16 + mrow)*LDA + quad*8;
  const u16* wBase = sW + mrow*LDA + quad*8;
  #pragma unroll
  for(int kk=0; kk<CIN; kk+=32){
    s8v af = *(const s8v*)(aBase + kk);
    #pragma unroll
    for(int ns=0; ns<NS; ns++){
      s8v bf = *(const s8v*)(wBase + ns*16*LDA + kk);
      acc[ns] = __builtin_amdgcn_mfma_f32_16x16x32_bf16(af, bf, acc[ns], 0, 0, 0);
    }
  }
  __syncthreads();   // done reading sW; safe to alias sdt/sbc
  int pr = p0 + wv*16 + quad*4;
  int prl = wv*16 + quad*4;
  #pragma unroll
  for(int ns=0; ns<NS; ns++){
    int n = ns*16 + mrow;
    if(n < 128){
      float bs = dtbias[n];
      #pragma unroll
      for(int r=0;r<4;r++){
        u16 v = f2b(softplus_(acc[ns][r] + bs));
        dtout[(size_t)(pr+r)*128 + n] = v;
        sdt[(prl+r)*128 + n] = v;
      }
    }else{
      #pragma unroll
      for(int r=0;r<4;r++){
        u16 v = f2b(acc[ns][r]);
        bcout[(size_t)(pr+r)*32 + (n-128)] = v;
        sbc[(prl+r)*32 + (n-128)] = v;
      }
    }
  }
  __syncthreads();
  int d = tid & 127;
  int b = p0 >> 12;
  int chb = (blockIdx.x & 63)*4;
  float A[16];
  #pragma unroll
  for(int s=0;s<16;s++) A[s] = -__expf(alog[d*16+s]);
  for(int cl = tid >> 7; cl < 4; cl += 2){
    float P[16], Q[16];
    #pragma unroll
    for(int s=0;s<16;s++){ P[s]=1.f; Q[s]=0.f; }
    #pragma unroll
    for(int i=0;i<CHL;i++){
      float dtv = b2f(sdt[(cl*16+i)*128 + d]);
      float xiv = b2f(sA[(cl*16+i)*LDA + d]);
      float u = dtv*xiv;
      #pragma unroll
      for(int s=0;s<16;s++){
        float a = __expf(dtv*A[s]);
        P[s] *= a;
        Q[s] = a*Q[s] + u*b2f(sbc[(cl*16+i)*32+s]);
      }
    }
    int gidx = (chb+cl)*16384 + (b*128+d)*16;
    unsigned pw[8], qw[8];
    #pragma unroll
    for(int j=0;j<8;j++){
      pw[j] = (unsigned)f2b(P[2*j]) | ((unsigned)f2b(P[2*j+1])<<16);
      qw[j] = (unsigned)f2b(Q[2*j]) | ((unsigned)f2b(Q[2*j+1])<<16);
    }
    *(uint4*)(Pb+gidx)   = make_uint4(pw[0],pw[1],pw[2],pw[3]);
    *(uint4*)(Pb+gidx+8) = make_uint4(pw[4],pw[5],pw[6],pw[7]);
    *(uint4*)(Qb+gidx)   = make_uint4(qw[0],qw[1],qw[2],qw[3]);
    *(uint4*)(Qb+gidx+8) = make_uint4(qw[4],qw[5],qw[6],qw[7]);
  }
}

// ---------------- scan phase 2 ----------------
__global__ void k_scan2(const u16* __restrict__ Pb, const u16* __restrict__ Qb,
                        u16* __restrict__ Hin){
  int g = blockIdx.x*64 + threadIdx.x;     // 16384 = (b,d,s)
  float h = 0.f;
  #pragma unroll 8
  for(int ch=0; ch<NCH; ch++){
    Hin[ch*16384 + g] = f2b(h);
    h = b2f(Pb[ch*16384 + g])*h + b2f(Qb[ch*16384 + g]);
  }
}

// ------- scan phase 3 + fused out-projection MFMA (y = outw@yss + x0) -------
__global__ __launch_bounds__(128) void k_scan3_mm(const u16* __restrict__ dt, const u16* __restrict__ xi,
                        const u16* __restrict__ bc, const u16* __restrict__ zs,
                        const float* __restrict__ alog, const float* __restrict__ Dp,
                        const u16* __restrict__ Hin, const u16* __restrict__ wout,
                        const u16* __restrict__ x0, u16* __restrict__ y){
  const int LDS2 = 136, LDW = 136;
  int blk = blockIdx.x;         // 2048 blocks of 128
  int ch = blk & (NCH-1);
  int b = blk >> 8;
  int d = threadIdx.x, tid = threadIdx.x;
  __shared__ __align__(16) u16 sdt[CHL*LDS2];   // dt in, yss out (in-place)
  __shared__ __align__(16) u16 sxi[CHL*128], szs[CHL*128], sbc[CHL*32];
  __shared__ __align__(16) u16 sWo[64*LDW];
  // stage out-weight [64][128]
  for(int idx=tid; idx<64*16; idx+=128){
    int n = idx>>4, c8 = (idx&15)*8;
    *(uint4*)(sWo + n*LDW + c8) = *(const uint4*)(wout + n*128 + c8);
  }
  float A[16], h[16];
  u16 hbuf[16];
  int gidx = ch*16384 + (b*128+d)*16;
  *(uint4*)hbuf     = *(const uint4*)(Hin+gidx);
  *(uint4*)(hbuf+8) = *(const uint4*)(Hin+gidx+8);
  #pragma unroll
  for(int s=0;s<16;s++){ A[s] = -__expf(alog[d*16+s]); h[s] = b2f(hbuf[s]); }
  float Dd = Dp[d];
  int pbase = b*HW_ + ch*CHL;
  // stage dt (padded rows), xi/zs/bc
  for(int idx=tid; idx<16*16; idx+=128){
    int i = idx>>4, c8 = (idx&15)*8;
    *(uint4*)(sdt + i*LDS2 + c8) = *(const uint4*)(dt + (size_t)(pbase+i)*128 + c8);
  }
  const uint4* gxi = (const uint4*)(xi + (size_t)pbase*128);
  const uint4* gzs = (const uint4*)(zs + (size_t)pbase*128);
  ((uint4*)sxi)[d]     = gxi[d];
  ((uint4*)sxi)[d+128] = gxi[d+128];
  ((uint4*)szs)[d]     = gzs[d];
  ((uint4*)szs)[d+128] = gzs[d+128];
  if(d < 64) ((uint4*)sbc)[d] = ((const uint4*)(bc + (size_t)pbase*32))[d];
  __syncthreads();
  #pragma unroll
  for(int i=0;i<CHL;i++){
    float dtv = b2f(sdt[i*LDS2+d]);
    float xiv = b2f(sxi[i*128+d]);
    float u = dtv*xiv;
    float acc = Dd*xiv;
    #pragma unroll
    for(int s=0;s<16;s++){
      float a = __expf(dtv*A[s]);
      h[s] = a*h[s] + u*b2f(sbc[i*32+s]);
      acc += h[s]*b2f(sbc[i*32+16+s]);
    }
    sdt[i*LDS2+d] = f2b(acc * b2f(szs[i*128+d]));   // yss in-place
  }
  __syncthreads();
  // out-projection: yss[16][128] @ wout^T -> y[16][64] (+ x0)
  int ln = tid & 63, wv = tid >> 6;
  int mrow = ln & 15, quad = ln >> 4;
  f4v acc2[2];
  acc2[0] = (f4v){0.f,0.f,0.f,0.f};
  acc2[1] = (f4v){0.f,0.f,0.f,0.f};
  #pragma unroll
  for(int kk=0; kk<128; kk+=32){
    s8v af = *(const s8v*)(sdt + mrow*LDS2 + kk + quad*8);
    #pragma unroll
    for(int ns=0; ns<2; ns++){
      int n0 = wv*32 + ns*16;
      s8v bf = *(const s8v*)(sWo + (n0+mrow)*LDW + kk + quad*8);
      acc2[ns] = __builtin_amdgcn_mfma_f32_16x16x32_bf16(af, bf, acc2[ns], 0, 0, 0);
    }
  }
  #pragma unroll
  for(int ns=0; ns<2; ns++){
    int n = wv*32 + ns*16 + mrow;
    #pragma unroll
    for(int r=0;r<4;r++){
      int px = pbase + quad*4 + r;
      y[(size_t)px*64 + n] = f2b(acc2[ns][r] + b2f(x0[(size_t)px*64 + n]));
    }
  }
}

// ========== MFMA with fused LayerNorm on A (CIN=64) ==========
template<int COUT, int ACT>
__global__ __launch_bounds__(256) void k_mfma_ln(const u16* __restrict__ wT,
                     const u16* __restrict__ in, const float* __restrict__ g,
                     const float* __restrict__ bta, u16* __restrict__ outp){
  const int CIN = 64, LDA = 72, NS = COUT/16;
  __shared__ __align__(16) u16 sA[64*LDA];
  __shared__ __align__(16) u16 sW[COUT*LDA];
  int tid = threadIdx.x;
  int p0 = blockIdx.x * 64;
  int ln = tid & 63, wv = tid >> 6;
  int mrow = ln & 15, quad = ln >> 4;
  for(int idx=tid; idx<COUT*8; idx+=256){
    int n = idx>>3, c8 = (idx&7)*8;
    *(uint4*)(sW + n*LDA + c8) = *(const uint4*)(wT + n*64 + c8);
  }
  float gg = g[ln], bb = bta[ln];
  #pragma unroll
  for(int i=0;i<16;i++){
    int row = wv*16 + i;
    float v = b2f(in[(size_t)(p0+row)*64 + ln]);
    float s = v, sq = v*v;
    #pragma unroll
    for(int o=32;o>0;o>>=1){ s += __shfl_xor(s,o); sq += __shfl_xor(sq,o); }
    float m = s*(1.f/64.f);
    float var = sq*(1.f/64.f) - m*m;
    float r = rsqrtf(var + 1e-5f);
    sA[row*LDA + ln] = f2b((v-m)*r*gg + bb);
  }
  __syncthreads();
  f4v acc[NS];
  #pragma unroll
  for(int i=0;i<NS;i++) acc[i] = (f4v){0.f,0.f,0.f,0.f};
  const u16* aBase = sA + (wv*16 + mrow)*LDA + quad*8;
  const u16* wBase = sW + mrow*LDA + quad*8;
  #pragma unroll
  for(int kk=0; kk<CIN; kk+=32){
    s8v af = *(const s8v*)(aBase + kk);
    #pragma unroll
    for(int ns=0; ns<NS; ns++){
      s8v bf = *(const s8v*)(wBase + ns*16*LDA + kk);
      acc[ns] = __builtin_amdgcn_mfma_f32_16x16x32_bf16(af, bf, acc[ns], 0, 0, 0);
    }
  }
  int pr = p0 + wv*16 + quad*4;
  #pragma unroll
  for(int ns=0; ns<NS; ns++){
    int n = ns*16 + mrow;
    #pragma unroll
    for(int r=0;r<4;r++){
      float v = acc[ns][r];
      if(ACT==1) v = leaky02(v);
      outp[(size_t)(pr+r)*COUT + n] = f2b(v);
    }
  }
}

// ========== final MFMA: [NPIX,256] @ wf2t[64][256] + res, fp32 NCHW store ==========
__global__ __launch_bounds__(256) void k_mfma_fin(const u16* __restrict__ wT,
                     const u16* __restrict__ in, const u16* __restrict__ res,
                     float* __restrict__ outp){
  const int CIN=256, COUT=64, KCH=128, LDA=136, NS=4;
  __shared__ __align__(16) u16 sA[64*LDA];
  __shared__ __align__(16) u16 sW[COUT*LDA];
  int tid = threadIdx.x;
  int p0 = blockIdx.x * 64;
  int ln = tid & 63, wv = tid >> 6;
  int mrow = ln & 15, quad = ln >> 4;
  f4v acc[NS];
  #pragma unroll
  for(int i=0;i<NS;i++) acc[i] = (f4v){0.f,0.f,0.f,0.f};
  const u16* aBase = sA + (wv*16 + mrow)*LDA + quad*8;
  const u16* wBase = sW + mrow*LDA + quad*8;
  for(int k0=0; k0<CIN; k0+=KCH){
    if(k0) __syncthreads();
    for(int idx=tid; idx<COUT*16; idx+=256){
      int n = idx>>4, c8 = (idx&15)*8;
      *(uint4*)(sW + n*LDA + c8) = *(const uint4*)(wT + n*256 + k0 + c8);
    }
    for(int g=tid; g<64*16; g+=256){
      int row = g >> 4, c8 = (g & 15)*8;
      *(uint4*)(sA + row*LDA + c8) = *(const uint4*)(in + (size_t)(p0+row)*CIN + k0 + c8);
    }
    __syncthreads();
    #pragma unroll
    for(int kk=0; kk<KCH; kk+=32){
      s8v af = *(const s8v*)(aBase + kk);
      #pragma unroll
      for(int ns=0; ns<NS; ns++){
        s8v bf = *(const s8v*)(wBase + ns*16*LDA + kk);
        acc[ns] = __builtin_amdgcn_mfma_f32_16x16x32_bf16(af, bf, acc[ns], 0, 0, 0);
      }
    }
  }
  int pr = p0 + wv*16 + quad*4;
  int b = blockIdx.x >> 6;
  int hwr = ((blockIdx.x & 63) << 6) + wv*16 + quad*4;
  #pragma unroll
  for(int ns=0; ns<NS; ns++){
    int n = ns*16 + mrow;
    float4 v4;
    v4.x = acc[ns][0] + b2f(res[(size_t)(pr+0)*64 + n]);
    v4.y = acc[ns][1] + b2f(res[(size_t)(pr+1)*64 + n]);
    v4.z = acc[ns][2] + b2f(res[(size_t)(pr+2)*64 + n]);
    v4.w = acc[ns][3] + b2f(res[(size_t)(pr+3)*64 + n]);
    *(float4*)(outp + (size_t)b*C_*HW_ + (size_t)n*HW_ + hwr) = v4;
  }
}

// ---------------- depthwise 3x3 SAME, 4 channels per thread ----------------
template<int CN, int ACT>   // ACT: 0 none, 1 leaky, 2 gelu
__global__ void k_dw3(const u16* __restrict__ in, const float* __restrict__ wgt,
                      const u16* __restrict__ res1, const u16* __restrict__ res2,
                      u16* __restrict__ out){
  const int C4 = CN/4;
  int g = blockIdx.x*256 + threadIdx.x;
  int c4 = g % C4;
  int pix = g / C4;
  int w = pix & 63;
  int h = (pix >> 6) & 63;
  int b = pix >> 12;
  float a0=0.f, a1=0.f, a2=0.f, a3=0.f;
  #pragma unroll
  for(int kh=0;kh<3;kh++){
    int hh = h + kh - 1;
    if((unsigned)hh < 64u){
      #pragma unroll
      for(int kw=0;kw<3;kw++){
        int ww = w + kw - 1;
        if((unsigned)ww < 64u){
          ushort4 v = *(const ushort4*)(in + (size_t)((b*64+hh)*64 + ww)*CN + c4*4);
          float4 wv = *(const float4*)(wgt + (kh*3+kw)*CN + c4*4);
          a0 += b2f(v.x)*wv.x; a1 += b2f(v.y)*wv.y;
          a2 += b2f(v.z)*wv.z; a3 += b2f(v.w)*wv.w;
        }
      }
    }
  }
  if(ACT==1){ a0=leaky02(a0); a1=leaky02(a1); a2=leaky02(a2); a3=leaky02(a3); }
  else if(ACT==2){ a0=gelu_exact(a0); a1=gelu_exact(a1); a2=gelu_exact(a2); a3=gelu_exact(a3); }
  size_t ob = (size_t)pix*CN + c4*4;
  if(res1){ ushort4 r = *(const ushort4*)(res1 + ob);
            a0+=b2f(r.x); a1+=b2f(r.y); a2+=b2f(r.z); a3+=b2f(r.w); }
  if(res2){ ushort4 r = *(const ushort4*)(res2 + ob);
            a0+=b2f(r.x); a1+=b2f(r.y); a2+=b2f(r.z); a3+=b2f(r.w); }
  ushort4 o; o.x=f2b(a0); o.y=f2b(a1); o.z=f2b(a2); o.w=f2b(a3);
  *(ushort4*)(out + ob) = o;
}

extern "C" void kernel_launch(void* const* d_in, const int* in_sizes, int n_in,
                              void* d_out, int out_size, void* d_ws, size_t ws_size,
                              hipStream_t stream) {
  const float* x        = (const float*)d_in[0];
  const float* ln1_g    = (const float*)d_in[1];
  const float* ln1_b    = (const float*)d_in[2];
  const float* vin_w1   = (const float*)d_in[3];
  const float* vin_dw   = (const float*)d_in[4];
  const float* vin_w2   = (const float*)d_in[5];
  const float* vout_dw1 = (const float*)d_in[6];
  const float* vout_dw2 = (const float*)d_in[7];
  const float* ssm_in_w = (const float*)d_in[8];
  const float* ssm_cw   = (const float*)d_in[9];
  const float* ssm_cb   = (const float*)d_in[10];
  const float* ssm_xprj = (const float*)d_in[11];
  const float* ssm_dtw  = (const float*)d_in[12];
  const float* ssm_dtb  = (const float*)d_in[13];
  const float* ssm_Alog = (const float*)d_in[14];
  const float* ssm_D    = (const float*)d_in[15];
  const float* ssm_outw = (const float*)d_in[16];
  const float* ln2_g    = (const float*)d_in[17];
  const float* ln2_b    = (const float*)d_in[18];
  const float* ff_w1    = (const float*)d_in[19];
  const float* ff_dw    = (const float*)d_in[20];
  const float* ff_w2    = (const float*)d_in[21];
  float* out = (float*)d_out;

  // ---- bf16 arena, lifetime-packed (units: bf16 elements) ----
  const size_t M = 1u<<20;
  u16* U   = (u16*)d_ws;
  u16* xT  = U;              // [0,2M)    lives to vision-out residual
  u16* tA  = U + 2*M;        // [2M,4M)   } Hin here during scan
  u16* tB  = U + 4*M;        // [4M,6M)   }
  u16* x0  = U + 6*M;        // [6M,8M)   x0, later xR
  u16* xi  = U + 8*M;        // [8M,12M)  xi
  u16* zs  = U + 12*M;       // [12M,16M) silu(z)
  u16* xz  = U + 16*M;       // [16M,24M) Pb/Qb during scan; y after; t1 in FFN
  u16* dtb = U + 24*M;       // [24M,28M) dt; t2 start in FFN
  u16* bc  = U + 28*M;       // [28M,29M)
  u16* Pb  = U + 16*M;       // [16M,20M)
  u16* Qb  = U + 20*M;       // [20M,24M)
  u16* Hin = tA;             // [2M,6M)
  u16* y   = U + 16*M;       // [16M,18M) (Pb/Qb dead once scan3_mm has Hin)
  u16* t2  = dtb;            // [24M,32M)
  // pre-transposed bf16 weights, past the working arena:
  u16* wv1  = U + 33*M;
  u16* wv2  = wv1 + 4096;
  u16* wsi  = wv2 + 4096;
  u16* wdb  = wsi + 16384;
  u16* wout = wdb + 20480;
  u16* wf1  = wout + 8192;
  u16* wf2t = wf1 + 16384;

  k_prep<<<80,256,0,stream>>>(vin_w1, vin_w2, ssm_in_w, ssm_xprj, ssm_dtw, ssm_outw,
                              ff_w1, ff_w2, wv1, wv2, wsi, wdb, wout, wf1, wf2t);

  // --- vision in path ---
  k_trans_ln_mm<<<512,256,0,stream>>>(x, ln1_g, ln1_b, wv1, xT, tB);
  k_dw3<64,2><<<2048,256,0,stream>>>(tB, vin_dw, nullptr, nullptr, tA);
  k_mfma<64,64,0,false><<<512,256,0,stream>>>(wv2, tA, nullptr, nullptr, x0);

  // --- SSM ---
  k_mfma_ssm<<<512,256,0,stream>>>(wsi, x0, ssm_cw, ssm_cb, xi, zs);
  k_dtbc_scan<<<512,256,0,stream>>>(wdb, xi, ssm_dtb, ssm_Alog, dtb, bc, Pb, Qb);
  k_scan2<<<256,64,0,stream>>>(Pb, Qb, Hin);
  k_scan3_mm<<<2048,128,0,stream>>>(dtb, xi, bc, zs, ssm_Alog, ssm_D, Hin, wout, x0, y);

  // --- vision out path:  xR = dw2(gelu(dw1(y))) + y + xT ---
  k_dw3<64,2><<<2048,256,0,stream>>>(y, vout_dw1, nullptr, nullptr, tA);
  k_dw3<64,0><<<2048,256,0,stream>>>(tA, vout_dw2, y, xT, x0);   // x0 now = xR

  // --- FFN (LN fused into ff_w1; trans_out fused into ff_w2) ---
  k_mfma_ln<256,1><<<512,256,0,stream>>>(wf1, x0, ln2_g, ln2_b, xz);  // t1
  k_dw3<256,1><<<8192,256,0,stream>>>(xz, ff_dw, nullptr, nullptr, t2);
  k_mfma_fin<<<512,256,0,stream>>>(wf2t, t2, x0, out);
}